// Round 10
// baseline (5370.160 us; speedup 1.0000x reference)
//
#include <hip/hip_runtime.h>
#include <math.h>

// DNC forward v10: two roles only. Role A (32 blocks): outproj + LSTM0,
// column-sliced, weights LDS-resident. Role C (32 blocks, one per batch):
// LSTM1 (streams Wx1/Wh1 from L2, 4-way k-split float4), IF matvec, memory
// module (R8's proven code). One hop pair per step: A->C (h0new), C->A
// (ctl + reads). h1/c1 are C-local LDS state.

#define TT   64
#define BB   32
#define INW  64
#define OUTW 64
#define NN   128
#define WD   64
#define RR   4
#define HH   256
#define IFSZ 471
#define CLIPV 20.0f
#define EPSV  1e-6f
#define NBLK 64

// interface vector offsets
#define OFF_RK   0
#define OFF_RSTR 256
#define OFF_WK   260
#define OFF_WSTR 324
#define OFF_ER   325
#define OFF_WV   389
#define OFF_FG   453
#define OFF_AG   457
#define OFF_WG   458
#define OFF_MD   459

// scal slots
#define S_WSTR 0
#define S_AG   1
#define S_WG   2
#define S_KNW  3
#define S_WSUM 4
#define S_RSTR 8
#define S_FG   12
#define S_KNR  16
#define S_BM   20
#define S_FM   24
#define S_CM   28

// ---- LDS layouts (floats) ----
// role A: Xs[320][37], Gl[32][33], c0[256], GO[64], Ws[576][37], WO[512][3]
#define A_XS   0
#define A_GL   11840
#define A_C0   12896
#define A_GO   13152
#define A_WS   13216
#define A_WO   34528
// role C: memory module + LSTM1 scratch
#define C_MS   0
#define C_LS   8320
#define C_WW   24832
#define C_PRC  24960
#define C_USG  25088
#define C_RWS  25216
#define C_IFC  25728
#define C_FWD  26208
#define C_BWD  26720
#define C_U2   27232
#define C_WCS  27360
#define C_RCS  27488
#define C_MNO  28000
#define C_ERS  28384
#define C_WVS  28448
#define C_SC   28512
#define C_SCAL 28576
#define C_HV   28608   // hvec[512] = [h0new_b | h1_b(persistent)]
#define C_C1   29120   // c1[256] persistent
#define C_CTL  29376   // ctl[256]
#define C_PART 29632   // part[4096] (LSTM1 k-split partials; IF uses first 1024)

#define SMEM_FLOATS 36064
#define SMEM_BYTES  (SMEM_FLOATS*4)

// ---- ws layout (floats), state vectors transposed [k][b] ----
#define W_CTL  0       // [256][32]
#define W_RDS  8192    // [256][32]
#define W_H0   16384   // [2][256*32]
#define W_FLA  49152   // fA: 32 slots x 32 (128B lines)
#define W_FLT  (W_FLA + 1024)  // fCt (ctl ready)
#define W_FLC  (W_FLT + 1024)  // fC (reads ready)
#define W_END  (W_FLC + 1024)

__device__ __forceinline__ float sigf(float x){ return 1.0f/(1.0f+expf(-x)); }
__device__ __forceinline__ float sofp(float x){ return fmaxf(x,0.0f)+log1pf(expf(-fabsf(x))); }

__device__ __forceinline__ float gload(const float* p){
  return __hip_atomic_load(p, __ATOMIC_RELAXED, __HIP_MEMORY_SCOPE_AGENT);
}
__device__ __forceinline__ void gstore(float* p, float v){
  __hip_atomic_store(p, v, __ATOMIC_RELAXED, __HIP_MEMORY_SCOPE_AGENT);
}

__device__ __forceinline__ void waitflag(const unsigned* slots, unsigned target){
  if (threadIdx.x < 64){
    for (;;){
      unsigned m = __hip_atomic_load(&slots[(threadIdx.x & 31)*32],
                                     __ATOMIC_RELAXED, __HIP_MEMORY_SCOPE_AGENT);
      #pragma unroll
      for (int s=32;s>0;s>>=1){
        unsigned o = (unsigned)__shfl_xor((int)m, s, 64);
        m = (o < m) ? o : m;
      }
      if (m >= target) break;
      __builtin_amdgcn_s_sleep(2);
    }
  }
  __syncthreads();
}

__device__ __forceinline__ void setflag(unsigned* slots, int g, unsigned val){
  asm volatile("s_waitcnt vmcnt(0)" ::: "memory");
  __syncthreads();
  if (threadIdx.x == 0)
    __hip_atomic_store(&slots[g*32], val, __ATOMIC_RELAXED, __HIP_MEMORY_SCOPE_AGENT);
}

__device__ __forceinline__ float wredSum(float v){
  #pragma unroll
  for (int m=32;m>0;m>>=1) v += __shfl_xor(v,m,64);
  return v;
}
__device__ __forceinline__ float wredMax(float v){
  #pragma unroll
  for (int m=32;m>0;m>>=1) v = fmaxf(v,__shfl_xor(v,m,64));
  return v;
}

// 6-stage butterfly reduce-scatter over 64 lanes
__device__ __forceinline__ float bfly64(float (&A)[64], int l, int* jb){
  #pragma unroll
  for (int st=0; st<6; ++st){
    const int m = 1<<st, half = 32>>st;
    const bool hi = (l & m) != 0;
    #pragma unroll
    for (int j=0;j<half;j++){
      float a = A[j], b = A[j+half];
      float keep = hi? b : a;
      float send = hi? a : b;
      A[j] = keep + __shfl_xor(send, m, 64);
    }
  }
  *jb = ((l&1)?32:0)|((l&2)?16:0)|((l&4)?8:0)|((l&8)?4:0)|((l&16)?2:0)|((l&32)?1:0);
  return A[0];
}

#define TILE_FMA(WBASE, WROW, XROW)                                      \
  {                                                                      \
    float xv[8], wv[8];                                                  \
    _Pragma("unroll")                                                    \
    for (int q=0;q<8;q++){                                               \
      wv[q] = sm[(WBASE) + (WROW)*37 + c0 + q];                          \
      xv[q] = Xs[(XROW)*37 + b0 + q];                                    \
    }                                                                    \
    _Pragma("unroll")                                                    \
    for (int bi=0;bi<8;bi++)                                             \
      _Pragma("unroll")                                                  \
      for (int ci=0;ci<8;ci++)                                           \
        acc[bi*8+ci] += xv[bi]*wv[ci];                                   \
  }

extern "C" __global__ __launch_bounds__(1024, 1)
void dnc_coop10(const float* __restrict__ inputs,
                const float* __restrict__ Wx0, const float* __restrict__ Wh0, const float* __restrict__ b0g,
                const float* __restrict__ Wx1, const float* __restrict__ Wh1, const float* __restrict__ b1g,
                const float* __restrict__ Wifg, const float* __restrict__ bifg,
                const float* __restrict__ Woutg, const float* __restrict__ boutg,
                float* __restrict__ outg, float* __restrict__ ws)
{
  const int bid  = blockIdx.x;
  const int role = bid >> 5;   // 0 = A, 1 = C
  const int g    = bid & 31;
  const int tid  = threadIdx.x;
  const int lane = tid & 63;
  const int wid  = tid >> 6;

  extern __shared__ float sm[];

  float* gctl  = ws + W_CTL;
  float* greads= ws + W_RDS;
  unsigned* fA = (unsigned*)(ws + W_FLA);
  unsigned* fCt= (unsigned*)(ws + W_FLT);
  unsigned* fC = (unsigned*)(ws + W_FLC);

  // ---- one-time staging + init (ws zeroed by host memset) ----
  if (role == 0){
    for (int i = tid; i < 576*32; i += 1024){
      int r = i >> 5, cl = i & 31;
      int cglob = 8*g + (cl&7) + ((cl>>3)<<8);
      float v;
      if (r < 256)      v = Wx0[(64+r)*1024 + cglob];
      else if (r < 320) v = Wx0[(r-256)*1024 + cglob];
      else              v = Wh0[(r-320)*1024 + cglob];
      sm[A_WS + r*37 + cl] = v;
    }
    for (int i = tid; i < 512*2; i += 1024){
      int k = i >> 1, c = i & 1;
      sm[A_WO + k*3 + c] = Woutg[k*64 + 2*g + c];
    }
    if (tid < 256) sm[A_C0 + tid] = 0.0f;
  } else {
    for (int i = tid; i < NN*65;  i += 1024) sm[C_MS + i] = 0.0f;
    for (int i = tid; i < NN*129; i += 1024) sm[C_LS + i] = 0.0f;
    if (tid < 128){ sm[C_WW+tid]=0.f; sm[C_PRC+tid]=0.f; sm[C_USG+tid]=0.f; }
    if (tid < 512) sm[C_RWS+tid]=0.f;
    if (tid < 512) sm[C_HV+tid]=0.f;          // h0 stage + h1 state
    if (tid < 256) sm[C_C1+tid]=0.f;
  }
  __syncthreads();

  if (role == 0){
    // =================== ROLE A: outproj(t-1) + LSTM0 ===================
    float* Xs = sm + A_XS;
    for (int t = 0; t <= TT; ++t){
      float* h0old = ws + W_H0 + (t&1)*8192;
      float* h0new = ws + W_H0 + ((t+1)&1)*8192;
      float acc[64]; float accO[16];

      waitflag(fA, (unsigned)t);
      if (t < TT){
        for (int i = tid; i < 256*32; i += 1024){
          int k = i>>5, bb = i&31; Xs[k*37+bb] = gload(&h0old[i]);
        }
        for (int i = tid; i < 64*32; i += 1024){
          int bb = i>>6, k = i&63;
          Xs[(256+k)*37+bb] = inputs[(t*BB + bb)*INW + k];
        }
        __syncthreads();
        #pragma unroll
        for (int j=0;j<64;j++) acc[j]=0.f;
        {
          const int b0 = (wid>>2)*8, c0 = (wid&3)*8;
          #pragma unroll
          for (int i=0;i<4;i++){
            int k = i*64 + lane;
            TILE_FMA(A_WS, 320+k, k)          // Wh0 @ h0old
          }
          TILE_FMA(A_WS, 256+lane, 256+lane)  // Wx(x) @ x_t
        }
        __syncthreads();
      }
      if (t > 0){
        waitflag(fCt, (unsigned)t);           // ctl(t-1) ready
        for (int i = tid; i < 256*32; i += 1024){
          int k = i>>5, bb = i&31; Xs[k*37+bb] = gload(&gctl[i]);
        }
        __syncthreads();
        #pragma unroll
        for (int j=0;j<16;j++) accO[j]=0.f;
        if (wid < 4){
          const int b0 = wid*8;
          #pragma unroll
          for (int i=0;i<4;i++){
            int k = i*64 + lane;
            float w0 = sm[A_WO + k*3], w1 = sm[A_WO + k*3 + 1];
            float xv[8];
            #pragma unroll
            for (int q=0;q<8;q++) xv[q] = Xs[k*37 + b0 + q];
            #pragma unroll
            for (int bi=0;bi<8;bi++){
              accO[bi*2]   += xv[bi]*w0;
              accO[bi*2+1] += xv[bi]*w1;
            }
          }
        }
        __syncthreads();
      }
      // --- critical path: reads(t-1) ---
      waitflag(fC, (unsigned)t);
      for (int i = tid; i < 256*32; i += 1024){
        int k = i>>5, bb = i&31; Xs[k*37+bb] = gload(&greads[i]);
      }
      __syncthreads();
      if (t < TT){
        {
          const int b0 = (wid>>2)*8, c0 = (wid&3)*8;
          #pragma unroll
          for (int i=0;i<4;i++){
            int k = i*64 + lane;
            TILE_FMA(A_WS, k, k)              // Wx(reads) @ reads
          }
          int jb; float v = bfly64(acc, lane, &jb);
          sm[A_GL + (b0 + (jb>>3))*33 + c0 + (jb&7)] = v;
        }
        __syncthreads();
        if (tid < 256){
          int bb = tid>>3, j = tid&7;
          float gi = sm[A_GL + bb*33 + j]      + b0g[8*g + j];
          float gf = sm[A_GL + bb*33 + 8 + j]  + b0g[256 + 8*g + j];
          float gg = sm[A_GL + bb*33 + 16 + j] + b0g[512 + 8*g + j];
          float go = sm[A_GL + bb*33 + 24 + j] + b0g[768 + 8*g + j];
          float c = sigf(gf)*sm[A_C0+tid] + sigf(gi)*tanhf(gg);
          sm[A_C0+tid] = c;
          gstore(&h0new[(8*g + j)*32 + bb], sigf(go)*tanhf(c));
        }
        setflag(fA, g, (unsigned)(t+1));      // unblock C ASAP
      }
      // --- off-critical: finish outproj(t-1) ---
      if (t > 0){
        if (wid < 4){
          const int b0 = wid*8;
          #pragma unroll
          for (int i=0;i<4;i++){
            int k = i*64 + lane;
            float w0 = sm[A_WO + (256+k)*3], w1 = sm[A_WO + (256+k)*3 + 1];
            float xv[8];
            #pragma unroll
            for (int q=0;q<8;q++) xv[q] = Xs[k*37 + b0 + q];
            #pragma unroll
            for (int bi=0;bi<8;bi++){
              accO[bi*2]   += xv[bi]*w0;
              accO[bi*2+1] += xv[bi]*w1;
            }
          }
          #pragma unroll
          for (int st=0; st<4; ++st){
            const int m = 1<<st, half = 8>>st;
            const bool hi = (lane & m) != 0;
            #pragma unroll
            for (int j=0;j<half;j++){
              float a = accO[j], b = accO[j+half];
              float keep = hi? b : a;
              float send = hi? a : b;
              accO[j] = keep + __shfl_xor(send, m, 64);
            }
          }
          accO[0] += __shfl_xor(accO[0], 16, 64);
          accO[0] += __shfl_xor(accO[0], 32, 64);
          int jb = ((lane&1)?8:0)|((lane&2)?4:0)|((lane&4)?2:0)|((lane&8)?1:0);
          if ((lane & 48) == 0){
            int bi = jb>>1, ci = jb&1;
            sm[A_GO + (wid*8+bi)*2 + ci] = accO[0];
          }
        }
        __syncthreads();
        if (tid < 64){
          int bb = tid>>1, c = tid&1;
          float v = sm[A_GO + tid] + boutg[2*g + c];
          outg[((t-1)*BB + bb)*OUTW + 2*g + c] = fminf(CLIPV, fmaxf(-CLIPV, v));
        }
      }
    }
  } else {
    // ===== ROLE C: LSTM1 (streamed) + IF + memory module (batch g) =====
    float* Ms  = sm + C_MS;
    float* Ls  = sm + C_LS;
    float* wws = sm + C_WW;
    float* prc = sm + C_PRC;
    float* usg = sm + C_USG;
    float* rws = sm + C_RWS;
    float* ifcl= sm + C_IFC;
    float* fwds= sm + C_FWD;
    float* bwds= sm + C_BWD;
    float* u2  = sm + C_U2;
    float* wcs = sm + C_WCS;
    float* rcs = sm + C_RCS;
    float* mno = sm + C_MNO;
    float* ers = sm + C_ERS;
    float* wvs = sm + C_WVS;
    float* sc  = sm + C_SC;
    float* scal= sm + C_SCAL;
    float* hvec= sm + C_HV;    // [0..255]=h0new_b, [256..511]=h1_b persistent
    float* c1l = sm + C_C1;
    float* ctl = sm + C_CTL;
    float* part= sm + C_PART;

    for (int t = 0; t < TT; ++t){
      float* h0new = ws + W_H0 + ((t+1)&1)*8192;

      // idle: ||M(t-1)||
      if (tid < 128){
        float s=0.f;
        #pragma unroll 8
        for (int d=0;d<WD;d++){ float v=Ms[tid*65+d]; s+=v*v; }
        mno[tid]=sqrtf(s);
      }
      // --- wait h0new(t) from A ---
      waitflag(fA, (unsigned)(t+1));
      if (tid < 256) hvec[tid] = gload(&h0new[tid*32 + g]);
      __syncthreads();
      // --- LSTM1 matvec: 4-way k-split, float4 cols ---
      {
        const int kq = tid >> 8, j4 = tid & 255;
        const float* Wb = (kq < 2) ? (Wx1 + (size_t)(kq*128)*1024 + 4*j4)
                                   : (Wh1 + (size_t)((kq-2)*128)*1024 + 4*j4);
        const float* xp = hvec + kq*128;
        float a0=0.f,a1=0.f,a2=0.f,a3=0.f;
        #pragma unroll 8
        for (int k=0;k<128;k++){
          float4 w = *reinterpret_cast<const float4*>(Wb + (size_t)k*1024);
          float x = xp[k];
          a0 += x*w.x; a1 += x*w.y; a2 += x*w.z; a3 += x*w.w;
        }
        *reinterpret_cast<float4*>(&part[kq*1024 + 4*j4]) = make_float4(a0,a1,a2,a3);
      }
      __syncthreads();
      if (tid < 256){
        const int j = tid;
        float gi=b1g[j], gf=b1g[256+j], gg=b1g[512+j], go=b1g[768+j];
        #pragma unroll
        for (int q=0;q<4;q++){
          const float* pp = part + q*1024;
          gi += pp[j]; gf += pp[256+j]; gg += pp[512+j]; go += pp[768+j];
        }
        float c = sigf(gf)*c1l[j] + sigf(gi)*tanhf(gg);
        c1l[j] = c;
        float h = sigf(go)*tanhf(c);
        hvec[256+j] = h;                      // h1 state for next step
        float cl = fminf(CLIPV, fmaxf(-CLIPV, h));
        ctl[j] = cl;
        gstore(&gctl[j*32 + g], cl);
      }
      setflag(fCt, g, (unsigned)(t+1));       // ctl published (incl. __syncthreads)

      // --- IF matvec: ifc = ctl @ Wif + bif (Wif streamed, ctl local) ---
      {
        const int kq = tid >> 9, c = tid & 511;
        if (c < IFSZ){
          const float* Wp = Wifg + (size_t)(kq*128)*IFSZ + c;
          const float* xp = ctl + kq*128;
          float a0=0.f, a1=0.f;
          #pragma unroll 8
          for (int k=0;k<128;k+=2){
            a0 += xp[k]   * Wp[(size_t)k*IFSZ];
            a1 += xp[k+1] * Wp[(size_t)(k+1)*IFSZ];
          }
          part[kq*512 + c] = a0 + a1;
        }
      }
      __syncthreads();
      if (tid < IFSZ) ifcl[tid] = part[tid] + part[512+tid] + bifg[tid];
      __syncthreads();

      // --- memory module (R8's proven phases) ---
      if (tid < RR){
        scal[S_RSTR+tid]=1.0f+sofp(ifcl[OFF_RSTR+tid]);
        scal[S_FG+tid]  =sigf(ifcl[OFF_FG+tid]);
        float m0=ifcl[OFF_MD+tid*3], m1=ifcl[OFF_MD+tid*3+1], m2=ifcl[OFF_MD+tid*3+2];
        float mx=fmaxf(m0,fmaxf(m1,m2));
        float e0=expf(m0-mx), e1=expf(m1-mx), e2=expf(m2-mx);
        float s=e0+e1+e2;
        scal[S_BM+tid]=e0/s; scal[S_FM+tid]=e1/s; scal[S_CM+tid]=e2/s;
      }
      if (tid == 4) scal[S_WSTR]=1.0f+sofp(ifcl[OFF_WSTR]);
      if (tid == 5) scal[S_AG]=sigf(ifcl[OFF_AG]);
      if (tid == 6) scal[S_WG]=sigf(ifcl[OFF_WG]);
      if (tid >= 64 && tid < 128){
        int d=tid-64;
        ers[d]=sigf(ifcl[OFF_ER+d]);
        wvs[d]=ifcl[OFF_WV+d];
      }
      if (wid == 8){
        float v=ifcl[OFF_WK+lane]; float s=wredSum(v*v);
        if (lane==0) scal[S_KNW]=sqrtf(s);
      }
      if (wid >= 10 && wid < 14){
        int r=wid-10; float v=ifcl[OFF_RK+r*WD+lane]; float s=wredSum(v*v);
        if (lane==0) scal[S_KNR+r]=sqrtf(s);
      }
      __syncthreads();
      if (tid < NN){
        float dot=0.f;
        #pragma unroll 8
        for (int d=0;d<WD;d++) dot += ifcl[OFF_WK+d]*Ms[tid*65+d];
        float sim = dot/(scal[S_KNW]*mno[tid]+EPSV);
        wcs[tid]=sim*scal[S_WSTR];
      }
      __syncthreads();
      if (tid < NN){ float mx=wredMax(wcs[tid]); if(lane==0) sc[wid]=mx; }
      __syncthreads();
      if (tid < NN){
        float mx=fmaxf(sc[0],sc[1]);
        float e=expf(wcs[tid]-mx);
        wcs[tid]=e;
        float s=wredSum(e); if(lane==0) sc[2+wid]=s;
      }
      __syncthreads();
      if (tid < NN) wcs[tid]=wcs[tid]/(sc[2]+sc[3]);
      __syncthreads();
      if (tid < NN){
        float cw = wws[tid];
        float u  = usg[tid] + (1.0f-usg[tid])*cw;
        float psi=1.0f;
        #pragma unroll
        for (int r=0;r<RR;r++) psi *= 1.0f - scal[S_FG+r]*rws[r*NN+tid];
        float us = u*psi;
        usg[tid]=us;
        u2[tid] = EPSV + (1.0f-EPSV)*us;
      }
      __syncthreads();
      if (tid < NN){
        float ui=u2[tid]; float p=1.0f;
        for (int j=0;j<NN;j++){
          float uj=u2[j];
          bool take = (uj<ui) || (uj==ui && j<tid);
          p *= take ? uj : 1.0f;
        }
        float a = (1.0f-ui)*p;
        float wwn = scal[S_WG]*( scal[S_AG]*a + (1.0f-scal[S_AG])*wcs[tid] );
        wws[tid]=wwn;
        float s=wredSum(wwn); if(lane==0) sc[wid]=s;
      }
      __syncthreads();
      if (tid==0) scal[S_WSUM]=sc[0]+sc[1];
      __syncthreads();
      #pragma unroll
      for (int i=0;i<8;i++){
        int el=tid+i*1024, n=el>>6, d=el&63;
        float w=wws[n];
        Ms[n*65+d] = Ms[n*65+d]*(1.0f - w*ers[d]) + w*wvs[d];
      }
      #pragma unroll
      for (int i=0;i<16;i++){
        int el=tid+i*1024, li=el>>7, lj=el&127;
        float v = (li==lj) ? 0.0f
                : (1.0f - wws[li] - wws[lj])*Ls[li*129+lj] + wws[li]*prc[lj];
        Ls[li*129+lj]=v;
      }
      __syncthreads();
      if (tid < NN) prc[tid] = (1.0f - scal[S_WSUM])*prc[tid] + wws[tid];
      if (tid >= 128 && tid < 256){
        int n=tid-128; float s=0.f;
        #pragma unroll 8
        for (int d=0;d<WD;d++){ float v=Ms[n*65+d]; s+=v*v; }
        mno[n]=sqrtf(s);
      }
      __syncthreads();
      if (tid < RR*NN){
        int r=tid>>7, n=tid&127;
        float dot=0.f;
        #pragma unroll 8
        for (int d=0;d<WD;d++) dot += ifcl[OFF_RK+r*WD+d]*Ms[n*65+d];
        float sim = dot/(scal[S_KNR+r]*mno[n]+EPSV);
        rcs[tid]=sim*scal[S_RSTR+r];
      }
      __syncthreads();
      if (tid < RR*NN){ float mx=wredMax(rcs[tid]); if(lane==0) sc[wid]=mx; }
      __syncthreads();
      if (tid < RR*NN){
        int r=tid>>7;
        float mx=fmaxf(sc[r*2],sc[r*2+1]);
        float e=expf(rcs[tid]-mx);
        rcs[tid]=e;
        float s=wredSum(e); if(lane==0) sc[8+wid]=s;
      }
      __syncthreads();
      if (tid < RR*NN){
        int r=tid>>7;
        rcs[tid]=rcs[tid]/(sc[8+r*2]+sc[9+r*2]);
      }
      __syncthreads();
      if (tid < RR*NN){
        int r=tid>>7, i=tid&127;
        float f=0.f, bw=0.f;
        const float* rwr = rws + r*NN;
        #pragma unroll 4
        for (int j=0;j<NN;j++){
          float rv=rwr[j];
          f  += Ls[i*129+j]*rv;
          bw += Ls[j*129+i]*rv;
        }
        fwds[tid]=f; bwds[tid]=bw;
      }
      __syncthreads();
      if (tid < RR*NN){
        int r=tid>>7;
        rws[tid] = scal[S_BM+r]*bwds[tid] + scal[S_CM+r]*rcs[tid] + scal[S_FM+r]*fwds[tid];
      }
      __syncthreads();
      if (tid < RR*WD){
        int r=tid>>6, d=tid&63;
        float s=0.f;
        #pragma unroll 8
        for (int n=0;n<NN;n++) s += rws[r*NN+n]*Ms[n*65+d];
        gstore(&greads[tid*32 + g], s);
      }
      setflag(fC, g, (unsigned)(t+1));
    }
  }
}

extern "C" void kernel_launch(void* const* d_in, const int* in_sizes, int n_in,
                              void* d_out, int out_size, void* d_ws, size_t ws_size,
                              hipStream_t stream)
{
  const float* inputs=(const float*)d_in[0];
  const float* Wx0   =(const float*)d_in[1];
  const float* Wh0   =(const float*)d_in[2];
  const float* b0    =(const float*)d_in[3];
  const float* Wx1   =(const float*)d_in[4];
  const float* Wh1   =(const float*)d_in[5];
  const float* b1    =(const float*)d_in[6];
  const float* Wif   =(const float*)d_in[7];
  const float* bif   =(const float*)d_in[8];
  const float* Wout  =(const float*)d_in[9];
  const float* bout  =(const float*)d_in[10];
  float* out = (float*)d_out;
  float* ws  = (float*)d_ws;

  hipMemsetAsync(ws, 0, W_END * sizeof(float), stream);

  hipFuncSetAttribute((const void*)dnc_coop10,
                      hipFuncAttributeMaxDynamicSharedMemorySize, SMEM_BYTES);

  void* args[] = { (void*)&inputs, (void*)&Wx0, (void*)&Wh0, (void*)&b0,
                   (void*)&Wx1, (void*)&Wh1, (void*)&b1, (void*)&Wif,
                   (void*)&bif, (void*)&Wout, (void*)&bout, (void*)&out,
                   (void*)&ws };
  hipLaunchCooperativeKernel((void*)dnc_coop10, dim3(NBLK), dim3(1024),
                             args, SMEM_BYTES, stream);
}

// Round 11
// 3135.028 us; speedup vs baseline: 1.7130x; 1.7130x over previous
//
#include <hip/hip_runtime.h>
#include <math.h>

// DNC forward v11 = R8 (best verified, 3352us) + two isolated changes:
// (1) role A posts fA right after the h0new store; outproj finish moved off
//     the critical path (sound half of R9).
// (2) cell-update thread remap (j=tid>>5, bb=tid&31) in A and B so the
//     h0new/h1new/gctl stores are contiguous (coalesced) per block.
// Role B and role C are byte-identical to R8.

#define TT   64
#define BB   32
#define INW  64
#define OUTW 64
#define NN   128
#define WD   64
#define RR   4
#define HH   256
#define IFSZ 471
#define CLIPV 20.0f
#define EPSV  1e-6f
#define NBLK 96

// interface vector offsets
#define OFF_RK   0
#define OFF_RSTR 256
#define OFF_WK   260
#define OFF_WSTR 324
#define OFF_ER   325
#define OFF_WV   389
#define OFF_FG   453
#define OFF_AG   457
#define OFF_WG   458
#define OFF_MD   459

// scal slots
#define S_WSTR 0
#define S_AG   1
#define S_WG   2
#define S_KNW  3
#define S_WSUM 4
#define S_RSTR 8
#define S_FG   12
#define S_KNR  16
#define S_BM   20
#define S_FM   24
#define S_CM   28

// ---- LDS layouts (floats) ----
#define A_XS   0
#define A_GL   11840
#define A_C0   12896
#define A_GO   13152
#define A_WS   13216
#define A_WO   34528
#define B_XS   0
#define B_GL   9472
#define B_C1   10528
#define B_W1   10784
#define C_MS   0
#define C_LS   8320
#define C_WW   24832
#define C_PRC  24960
#define C_USG  25088
#define C_RWS  25216
#define C_IFC  25728
#define C_FWD  26208    // also part[1024] for IF matvec
#define C_BWD  26720
#define C_U2   27232
#define C_WCS  27360
#define C_RCS  27488    // also ctl_l[256] staging for IF
#define C_MNO  28000
#define C_RDS  28128
#define C_ERS  28384
#define C_WVS  28448
#define C_SC   28512
#define C_SCAL 28576

#define SMEM_FLOATS 36064
#define SMEM_BYTES  (SMEM_FLOATS*4)

// ---- ws layout (floats), state vectors transposed [k][b] ----
#define W_CTL  0       // [256][32]
#define W_RDS  8192    // [256][32]
#define W_H0   16384   // [2][256*32]
#define W_H1   32768   // [2][256*32]
#define W_FLA  49152
#define W_FLB  (W_FLA + 1024)
#define W_FLC  (W_FLB + 1024)
#define W_END  (W_FLC + 1024)

__device__ __forceinline__ float sigf(float x){ return 1.0f/(1.0f+expf(-x)); }
__device__ __forceinline__ float sofp(float x){ return fmaxf(x,0.0f)+log1pf(expf(-fabsf(x))); }

__device__ __forceinline__ float gload(const float* p){
  return __hip_atomic_load(p, __ATOMIC_RELAXED, __HIP_MEMORY_SCOPE_AGENT);
}
__device__ __forceinline__ void gstore(float* p, float v){
  __hip_atomic_store(p, v, __ATOMIC_RELAXED, __HIP_MEMORY_SCOPE_AGENT);
}

__device__ __forceinline__ void waitflag(const unsigned* slots, unsigned target){
  if (threadIdx.x < 64){
    for (;;){
      unsigned m = __hip_atomic_load(&slots[(threadIdx.x & 31)*32],
                                     __ATOMIC_RELAXED, __HIP_MEMORY_SCOPE_AGENT);
      #pragma unroll
      for (int s=32;s>0;s>>=1){
        unsigned o = (unsigned)__shfl_xor((int)m, s, 64);
        m = (o < m) ? o : m;
      }
      if (m >= target) break;
      __builtin_amdgcn_s_sleep(2);
    }
  }
  __syncthreads();
}

__device__ __forceinline__ void setflag(unsigned* slots, int g, unsigned val){
  asm volatile("s_waitcnt vmcnt(0)" ::: "memory");
  __syncthreads();
  if (threadIdx.x == 0)
    __hip_atomic_store(&slots[g*32], val, __ATOMIC_RELAXED, __HIP_MEMORY_SCOPE_AGENT);
}

__device__ __forceinline__ float wredSum(float v){
  #pragma unroll
  for (int m=32;m>0;m>>=1) v += __shfl_xor(v,m,64);
  return v;
}
__device__ __forceinline__ float wredMax(float v){
  #pragma unroll
  for (int m=32;m>0;m>>=1) v = fmaxf(v,__shfl_xor(v,m,64));
  return v;
}

// 6-stage butterfly reduce-scatter over 64 lanes
__device__ __forceinline__ float bfly64(float (&A)[64], int l, int* jb){
  #pragma unroll
  for (int st=0; st<6; ++st){
    const int m = 1<<st, half = 32>>st;
    const bool hi = (l & m) != 0;
    #pragma unroll
    for (int j=0;j<half;j++){
      float a = A[j], b = A[j+half];
      float keep = hi? b : a;
      float send = hi? a : b;
      A[j] = keep + __shfl_xor(send, m, 64);
    }
  }
  *jb = ((l&1)?32:0)|((l&2)?16:0)|((l&4)?8:0)|((l&8)?4:0)|((l&16)?2:0)|((l&32)?1:0);
  return A[0];
}

#define TILE_FMA(WBASE, WROW, XROW)                                      \
  {                                                                      \
    float xv[8], wv[8];                                                  \
    _Pragma("unroll")                                                    \
    for (int q=0;q<8;q++){                                               \
      wv[q] = sm[(WBASE) + (WROW)*37 + c0 + q];                          \
      xv[q] = Xs[(XROW)*37 + b0 + q];                                    \
    }                                                                    \
    _Pragma("unroll")                                                    \
    for (int bi=0;bi<8;bi++)                                             \
      _Pragma("unroll")                                                  \
      for (int ci=0;ci<8;ci++)                                           \
        acc[bi*8+ci] += xv[bi]*wv[ci];                                   \
  }

extern "C" __global__ __launch_bounds__(1024, 1)
void dnc_coop11(const float* __restrict__ inputs,
                const float* __restrict__ Wx0, const float* __restrict__ Wh0, const float* __restrict__ b0g,
                const float* __restrict__ Wx1, const float* __restrict__ Wh1, const float* __restrict__ b1g,
                const float* __restrict__ Wifg, const float* __restrict__ bifg,
                const float* __restrict__ Woutg, const float* __restrict__ boutg,
                float* __restrict__ outg, float* __restrict__ ws)
{
  const int bid  = blockIdx.x;
  const int role = bid >> 5;
  const int g    = bid & 31;
  const int tid  = threadIdx.x;
  const int lane = tid & 63;
  const int wid  = tid >> 6;

  extern __shared__ float sm[];

  float* gctl  = ws + W_CTL;
  float* greads= ws + W_RDS;
  unsigned* fA = (unsigned*)(ws + W_FLA);
  unsigned* fB = (unsigned*)(ws + W_FLB);
  unsigned* fC = (unsigned*)(ws + W_FLC);

  // ---- one-time weight staging + state init ----
  if (role == 0){
    for (int i = tid; i < 576*32; i += 1024){
      int r = i >> 5, cl = i & 31;
      int cglob = 8*g + (cl&7) + ((cl>>3)<<8);
      float v;
      if (r < 256)      v = Wx0[(64+r)*1024 + cglob];
      else if (r < 320) v = Wx0[(r-256)*1024 + cglob];
      else              v = Wh0[(r-320)*1024 + cglob];
      sm[A_WS + r*37 + cl] = v;
    }
    for (int i = tid; i < 512*2; i += 1024){
      int k = i >> 1, c = i & 1;
      sm[A_WO + k*3 + c] = Woutg[k*64 + 2*g + c];
    }
    if (tid < 256) sm[A_C0 + tid] = 0.0f;
  } else if (role == 1){
    for (int i = tid; i < 512*32; i += 1024){
      int r = i >> 5, cl = i & 31;
      int cglob = 8*g + (cl&7) + ((cl>>3)<<8);
      sm[B_W1 + r*37 + cl] = (r < 256) ? Wx1[r*1024 + cglob]
                                       : Wh1[(r-256)*1024 + cglob];
    }
    if (tid < 256) sm[B_C1 + tid] = 0.0f;
  } else {
    for (int i = tid; i < NN*65;  i += 1024) sm[C_MS + i] = 0.0f;
    for (int i = tid; i < NN*129; i += 1024) sm[C_LS + i] = 0.0f;
    if (tid < 128){ sm[C_WW+tid]=0.f; sm[C_PRC+tid]=0.f; sm[C_USG+tid]=0.f; }
    if (tid < 512) sm[C_RWS+tid]=0.f;
  }
  __syncthreads();

  if (role == 0){
    // =================== ROLE A: LSTM0 (+ outproj off-path) ===================
    float* Xs = sm + A_XS;
    for (int t = 0; t <= TT; ++t){
      float* h0old = ws + W_H0 + (t&1)*8192;
      float* h0new = ws + W_H0 + ((t+1)&1)*8192;
      float acc[64]; float accO[16];

      // --- idle-window: h0-chunk + x-chunk ---
      waitflag(fA, (unsigned)t);
      if (t < TT){
        for (int i = tid; i < 256*32; i += 1024){
          int k = i>>5, bb = i&31; Xs[k*37+bb] = gload(&h0old[i]);
        }
        for (int i = tid; i < 64*32; i += 1024){
          int bb = i>>6, k = i&63;
          Xs[(256+k)*37+bb] = inputs[(t*BB + bb)*INW + k];
        }
        __syncthreads();
        #pragma unroll
        for (int j=0;j<64;j++) acc[j]=0.f;
        {
          const int b0 = (wid>>2)*8, c0 = (wid&3)*8;
          #pragma unroll
          for (int i=0;i<4;i++){
            int k = i*64 + lane;
            TILE_FMA(A_WS, 320+k, k)          // Wh0 @ h0old
          }
          TILE_FMA(A_WS, 256+lane, 256+lane)  // Wx(x) @ x_t
        }
        __syncthreads();
      }
      // --- idle-window: outproj ctl-half ---
      if (t > 0){
        waitflag(fB, (unsigned)t);
        for (int i = tid; i < 256*32; i += 1024){
          int k = i>>5, bb = i&31; Xs[k*37+bb] = gload(&gctl[i]);
        }
        __syncthreads();
        #pragma unroll
        for (int j=0;j<16;j++) accO[j]=0.f;
        if (wid < 4){
          const int b0 = wid*8;
          #pragma unroll
          for (int i=0;i<4;i++){
            int k = i*64 + lane;
            float w0 = sm[A_WO + k*3], w1 = sm[A_WO + k*3 + 1];
            float xv[8];
            #pragma unroll
            for (int q=0;q<8;q++) xv[q] = Xs[k*37 + b0 + q];
            #pragma unroll
            for (int bi=0;bi<8;bi++){
              accO[bi*2]   += xv[bi]*w0;
              accO[bi*2+1] += xv[bi]*w1;
            }
          }
        }
        __syncthreads();
      }
      // --- critical path: reads(t-1) ---
      waitflag(fC, (unsigned)t);
      for (int i = tid; i < 256*32; i += 1024){
        int k = i>>5, bb = i&31; Xs[k*37+bb] = gload(&greads[i]);
      }
      __syncthreads();
      if (t < TT){
        {
          const int b0 = (wid>>2)*8, c0 = (wid&3)*8;
          #pragma unroll
          for (int i=0;i<4;i++){
            int k = i*64 + lane;
            TILE_FMA(A_WS, k, k)              // Wx(reads) @ reads
          }
          int jb; float v = bfly64(acc, lane, &jb);
          sm[A_GL + (b0 + (jb>>3))*33 + c0 + (jb&7)] = v;
        }
        __syncthreads();
        if (tid < 256){
          int j = tid>>5, bb = tid&31;        // coalesced-store remap
          float gi = sm[A_GL + bb*33 + j]      + b0g[8*g + j];
          float gf = sm[A_GL + bb*33 + 8 + j]  + b0g[256 + 8*g + j];
          float gg = sm[A_GL + bb*33 + 16 + j] + b0g[512 + 8*g + j];
          float go = sm[A_GL + bb*33 + 24 + j] + b0g[768 + 8*g + j];
          float c = sigf(gf)*sm[A_C0 + j*32 + bb] + sigf(gi)*tanhf(gg);
          sm[A_C0 + j*32 + bb] = c;
          gstore(&h0new[256*g + tid], sigf(go)*tanhf(c));   // contiguous
        }
        setflag(fA, g, (unsigned)(t+1));      // unblock B ASAP
      }
      // --- off-critical: finish outproj(t-1) ---
      if (t > 0){
        if (wid < 4){
          const int b0 = wid*8;
          #pragma unroll
          for (int i=0;i<4;i++){
            int k = i*64 + lane;
            float w0 = sm[A_WO + (256+k)*3], w1 = sm[A_WO + (256+k)*3 + 1];
            float xv[8];
            #pragma unroll
            for (int q=0;q<8;q++) xv[q] = Xs[k*37 + b0 + q];
            #pragma unroll
            for (int bi=0;bi<8;bi++){
              accO[bi*2]   += xv[bi]*w0;
              accO[bi*2+1] += xv[bi]*w1;
            }
          }
          #pragma unroll
          for (int st=0; st<4; ++st){
            const int m = 1<<st, half = 8>>st;
            const bool hi = (lane & m) != 0;
            #pragma unroll
            for (int j=0;j<half;j++){
              float a = accO[j], b = accO[j+half];
              float keep = hi? b : a;
              float send = hi? a : b;
              accO[j] = keep + __shfl_xor(send, m, 64);
            }
          }
          accO[0] += __shfl_xor(accO[0], 16, 64);
          accO[0] += __shfl_xor(accO[0], 32, 64);
          int jb = ((lane&1)?8:0)|((lane&2)?4:0)|((lane&4)?2:0)|((lane&8)?1:0);
          if ((lane & 48) == 0){
            int bi = jb>>1, ci = jb&1;
            sm[A_GO + (wid*8+bi)*2 + ci] = accO[0];
          }
        }
        __syncthreads();
        if (tid < 64){
          int bb = tid>>1, c = tid&1;
          float v = sm[A_GO + tid] + boutg[2*g + c];
          outg[((t-1)*BB + bb)*OUTW + 2*g + c] = fminf(CLIPV, fmaxf(-CLIPV, v));
        }
      }
    }
  } else if (role == 1){
    // =================== ROLE B: LSTM1 (identical to R8 except remap) ========
    float* Xs = sm + B_XS;
    for (int t = 0; t < TT; ++t){
      float* h0new = ws + W_H0 + ((t+1)&1)*8192;
      float* h1old = ws + W_H1 + (t&1)*8192;
      float* h1new = ws + W_H1 + ((t+1)&1)*8192;
      float acc[64];
      #pragma unroll
      for (int j=0;j<64;j++) acc[j]=0.f;

      waitflag(fB, (unsigned)t);
      for (int i = tid; i < 256*32; i += 1024){
        int k = i>>5, bb = i&31; Xs[k*37+bb] = gload(&h1old[i]);
      }
      __syncthreads();
      {
        const int b0 = (wid>>2)*8, c0 = (wid&3)*8;
        #pragma unroll
        for (int i=0;i<4;i++){
          int k = i*64 + lane;
          TILE_FMA(B_W1, 256+k, k)
        }
      }
      __syncthreads();
      waitflag(fA, (unsigned)(t+1));
      for (int i = tid; i < 256*32; i += 1024){
        int k = i>>5, bb = i&31; Xs[k*37+bb] = gload(&h0new[i]);
      }
      __syncthreads();
      {
        const int b0 = (wid>>2)*8, c0 = (wid&3)*8;
        #pragma unroll
        for (int i=0;i<4;i++){
          int k = i*64 + lane;
          TILE_FMA(B_W1, k, k)
        }
        int jb; float v = bfly64(acc, lane, &jb);
        sm[B_GL + (b0 + (jb>>3))*33 + c0 + (jb&7)] = v;
      }
      __syncthreads();
      if (tid < 256){
        int j = tid>>5, bb = tid&31;          // coalesced-store remap
        float gi = sm[B_GL + bb*33 + j]      + b1g[8*g + j];
        float gf = sm[B_GL + bb*33 + 8 + j]  + b1g[256 + 8*g + j];
        float gg = sm[B_GL + bb*33 + 16 + j] + b1g[512 + 8*g + j];
        float go = sm[B_GL + bb*33 + 24 + j] + b1g[768 + 8*g + j];
        float c = sigf(gf)*sm[B_C1 + j*32 + bb] + sigf(gi)*tanhf(gg);
        sm[B_C1 + j*32 + bb] = c;
        float h = sigf(go)*tanhf(c);
        gstore(&h1new[256*g + tid], h);                    // contiguous
        gstore(&gctl[256*g + tid], fminf(CLIPV, fmaxf(-CLIPV, h)));
      }
      setflag(fB, g, (unsigned)(t+1));
    }
  } else {
    // =================== ROLE C: IF matvec + memory module (R8 verbatim) =====
    float* Ms  = sm + C_MS;
    float* Ls  = sm + C_LS;
    float* wws = sm + C_WW;
    float* prc = sm + C_PRC;
    float* usg = sm + C_USG;
    float* rws = sm + C_RWS;
    float* ifcl= sm + C_IFC;
    float* fwds= sm + C_FWD;
    float* bwds= sm + C_BWD;
    float* u2  = sm + C_U2;
    float* wcs = sm + C_WCS;
    float* rcs = sm + C_RCS;
    float* mno = sm + C_MNO;
    float* ers = sm + C_ERS;
    float* wvs = sm + C_WVS;
    float* sc  = sm + C_SC;
    float* scal= sm + C_SCAL;
    float* ctl_l = sm + C_RCS;
    float* part  = sm + C_FWD;

    for (int t = 0; t < TT; ++t){
      if (tid < 128){
        float s=0.f;
        #pragma unroll 8
        for (int d=0;d<WD;d++){ float v=Ms[tid*65+d]; s+=v*v; }
        mno[tid]=sqrtf(s);
      }
      waitflag(fB, (unsigned)(t+1));
      if (tid < 256) ctl_l[tid] = gload(&gctl[tid*32 + g]);
      __syncthreads();
      {
        const int kq = tid >> 9, c = tid & 511;
        if (c < IFSZ){
          const float* Wp = Wifg + (size_t)(kq*128)*IFSZ + c;
          const float* xp = ctl_l + kq*128;
          float a0=0.f, a1=0.f;
          #pragma unroll 8
          for (int k=0;k<128;k+=2){
            a0 += xp[k]   * Wp[(size_t)k*IFSZ];
            a1 += xp[k+1] * Wp[(size_t)(k+1)*IFSZ];
          }
          part[kq*512 + c] = a0 + a1;
        }
      }
      __syncthreads();
      if (tid < IFSZ) ifcl[tid] = part[tid] + part[512+tid] + bifg[tid];
      __syncthreads();

      if (tid < RR){
        scal[S_RSTR+tid]=1.0f+sofp(ifcl[OFF_RSTR+tid]);
        scal[S_FG+tid]  =sigf(ifcl[OFF_FG+tid]);
        float m0=ifcl[OFF_MD+tid*3], m1=ifcl[OFF_MD+tid*3+1], m2=ifcl[OFF_MD+tid*3+2];
        float mx=fmaxf(m0,fmaxf(m1,m2));
        float e0=expf(m0-mx), e1=expf(m1-mx), e2=expf(m2-mx);
        float s=e0+e1+e2;
        scal[S_BM+tid]=e0/s; scal[S_FM+tid]=e1/s; scal[S_CM+tid]=e2/s;
      }
      if (tid == 4) scal[S_WSTR]=1.0f+sofp(ifcl[OFF_WSTR]);
      if (tid == 5) scal[S_AG]=sigf(ifcl[OFF_AG]);
      if (tid == 6) scal[S_WG]=sigf(ifcl[OFF_WG]);
      if (tid >= 64 && tid < 128){
        int d=tid-64;
        ers[d]=sigf(ifcl[OFF_ER+d]);
        wvs[d]=ifcl[OFF_WV+d];
      }
      if (wid == 8){
        float v=ifcl[OFF_WK+lane]; float s=wredSum(v*v);
        if (lane==0) scal[S_KNW]=sqrtf(s);
      }
      if (wid >= 10 && wid < 14){
        int r=wid-10; float v=ifcl[OFF_RK+r*WD+lane]; float s=wredSum(v*v);
        if (lane==0) scal[S_KNR+r]=sqrtf(s);
      }
      __syncthreads();
      if (tid < NN){
        float dot=0.f;
        #pragma unroll 8
        for (int d=0;d<WD;d++) dot += ifcl[OFF_WK+d]*Ms[tid*65+d];
        float sim = dot/(scal[S_KNW]*mno[tid]+EPSV);
        wcs[tid]=sim*scal[S_WSTR];
      }
      __syncthreads();
      if (tid < NN){ float mx=wredMax(wcs[tid]); if(lane==0) sc[wid]=mx; }
      __syncthreads();
      if (tid < NN){
        float mx=fmaxf(sc[0],sc[1]);
        float e=expf(wcs[tid]-mx);
        wcs[tid]=e;
        float s=wredSum(e); if(lane==0) sc[2+wid]=s;
      }
      __syncthreads();
      if (tid < NN) wcs[tid]=wcs[tid]/(sc[2]+sc[3]);
      __syncthreads();
      if (tid < NN){
        float cw = wws[tid];
        float u  = usg[tid] + (1.0f-usg[tid])*cw;
        float psi=1.0f;
        #pragma unroll
        for (int r=0;r<RR;r++) psi *= 1.0f - scal[S_FG+r]*rws[r*NN+tid];
        float us = u*psi;
        usg[tid]=us;
        u2[tid] = EPSV + (1.0f-EPSV)*us;
      }
      __syncthreads();
      if (tid < NN){
        float ui=u2[tid]; float p=1.0f;
        for (int j=0;j<NN;j++){
          float uj=u2[j];
          bool take = (uj<ui) || (uj==ui && j<tid);
          p *= take ? uj : 1.0f;
        }
        float a = (1.0f-ui)*p;
        float wwn = scal[S_WG]*( scal[S_AG]*a + (1.0f-scal[S_AG])*wcs[tid] );
        wws[tid]=wwn;
        float s=wredSum(wwn); if(lane==0) sc[wid]=s;
      }
      __syncthreads();
      if (tid==0) scal[S_WSUM]=sc[0]+sc[1];
      __syncthreads();
      #pragma unroll
      for (int i=0;i<8;i++){
        int el=tid+i*1024, n=el>>6, d=el&63;
        float w=wws[n];
        Ms[n*65+d] = Ms[n*65+d]*(1.0f - w*ers[d]) + w*wvs[d];
      }
      #pragma unroll
      for (int i=0;i<16;i++){
        int el=tid+i*1024, li=el>>7, lj=el&127;
        float v = (li==lj) ? 0.0f
                : (1.0f - wws[li] - wws[lj])*Ls[li*129+lj] + wws[li]*prc[lj];
        Ls[li*129+lj]=v;
      }
      __syncthreads();
      if (tid < NN) prc[tid] = (1.0f - scal[S_WSUM])*prc[tid] + wws[tid];
      if (tid >= 128 && tid < 256){
        int n=tid-128; float s=0.f;
        #pragma unroll 8
        for (int d=0;d<WD;d++){ float v=Ms[n*65+d]; s+=v*v; }
        mno[n]=sqrtf(s);
      }
      __syncthreads();
      if (tid < RR*NN){
        int r=tid>>7, n=tid&127;
        float dot=0.f;
        #pragma unroll 8
        for (int d=0;d<WD;d++) dot += ifcl[OFF_RK+r*WD+d]*Ms[n*65+d];
        float sim = dot/(scal[S_KNR+r]*mno[n]+EPSV);
        rcs[tid]=sim*scal[S_RSTR+r];
      }
      __syncthreads();
      if (tid < RR*NN){ float mx=wredMax(rcs[tid]); if(lane==0) sc[wid]=mx; }
      __syncthreads();
      if (tid < RR*NN){
        int r=tid>>7;
        float mx=fmaxf(sc[r*2],sc[r*2+1]);
        float e=expf(rcs[tid]-mx);
        rcs[tid]=e;
        float s=wredSum(e); if(lane==0) sc[8+wid]=s;
      }
      __syncthreads();
      if (tid < RR*NN){
        int r=tid>>7;
        rcs[tid]=rcs[tid]/(sc[8+r*2]+sc[9+r*2]);
      }
      __syncthreads();
      if (tid < RR*NN){
        int r=tid>>7, i=tid&127;
        float f=0.f, bw=0.f;
        const float* rwr = rws + r*NN;
        #pragma unroll 4
        for (int j=0;j<NN;j++){
          float rv=rwr[j];
          f  += Ls[i*129+j]*rv;
          bw += Ls[j*129+i]*rv;
        }
        fwds[tid]=f; bwds[tid]=bw;
      }
      __syncthreads();
      if (tid < RR*NN){
        int r=tid>>7;
        rws[tid] = scal[S_BM+r]*bwds[tid] + scal[S_CM+r]*rcs[tid] + scal[S_FM+r]*fwds[tid];
      }
      __syncthreads();
      if (tid < RR*WD){
        int r=tid>>6, d=tid&63;
        float s=0.f;
        #pragma unroll 8
        for (int n=0;n<NN;n++) s += rws[r*NN+n]*Ms[n*65+d];
        gstore(&greads[tid*32 + g], s);
      }
      setflag(fC, g, (unsigned)(t+1));
    }
  }
}

extern "C" void kernel_launch(void* const* d_in, const int* in_sizes, int n_in,
                              void* d_out, int out_size, void* d_ws, size_t ws_size,
                              hipStream_t stream)
{
  const float* inputs=(const float*)d_in[0];
  const float* Wx0   =(const float*)d_in[1];
  const float* Wh0   =(const float*)d_in[2];
  const float* b0    =(const float*)d_in[3];
  const float* Wx1   =(const float*)d_in[4];
  const float* Wh1   =(const float*)d_in[5];
  const float* b1    =(const float*)d_in[6];
  const float* Wif   =(const float*)d_in[7];
  const float* bif   =(const float*)d_in[8];
  const float* Wout  =(const float*)d_in[9];
  const float* bout  =(const float*)d_in[10];
  float* out = (float*)d_out;
  float* ws  = (float*)d_ws;

  hipMemsetAsync(ws, 0, W_END * sizeof(float), stream);

  hipFuncSetAttribute((const void*)dnc_coop11,
                      hipFuncAttributeMaxDynamicSharedMemorySize, SMEM_BYTES);

  void* args[] = { (void*)&inputs, (void*)&Wx0, (void*)&Wh0, (void*)&b0,
                   (void*)&Wx1, (void*)&Wh1, (void*)&b1, (void*)&Wif,
                   (void*)&bif, (void*)&Wout, (void*)&bout, (void*)&out,
                   (void*)&ws };
  hipLaunchCooperativeKernel((void*)dnc_coop11, dim3(NBLK), dim3(1024),
                             args, SMEM_BYTES, stream);
}

// Round 12
// 3006.665 us; speedup vs baseline: 1.7861x; 1.0427x over previous
//
#include <hip/hip_runtime.h>
#include <math.h>

// DNC forward v12 = R11 roles A/B verbatim + role C serial-chain compression:
// fwd/bwd overlapped with rcs-dot, mnorm fused into rcs, usage overlapped
// with wc-dot, normalizations fused into consumers, prec folded into the
// rw phase, IF matvec 4-way k-split, reads matvec widened to 1024 threads.
// All phases stay >=128 threads wide (R9's narrow-wave mistake avoided).

#define TT   64
#define BB   32
#define INW  64
#define OUTW 64
#define NN   128
#define WD   64
#define RR   4
#define HH   256
#define IFSZ 471
#define CLIPV 20.0f
#define EPSV  1e-6f
#define NBLK 96

// interface vector offsets
#define OFF_RK   0
#define OFF_RSTR 256
#define OFF_WK   260
#define OFF_WSTR 324
#define OFF_ER   325
#define OFF_WV   389
#define OFF_FG   453
#define OFF_AG   457
#define OFF_WG   458
#define OFF_MD   459

// scal slots
#define S_WSTR 0
#define S_AG   1
#define S_WG   2
#define S_KNW  3
#define S_RSTR 8
#define S_FG   12
#define S_KNR  16
#define S_BM   20
#define S_FM   24
#define S_CM   28

// ---- LDS layouts (floats) ----
#define A_XS   0
#define A_GL   11840
#define A_C0   12896
#define A_GO   13152
#define A_WS   13216
#define A_WO   34528
#define B_XS   0
#define B_GL   9472
#define B_C1   10528
#define B_W1   10784
#define C_MS   0
#define C_LS   8320
#define C_WW   24832
#define C_PRC  24960
#define C_USG  25088
#define C_RWS  25216
#define C_IFC  25728
#define C_FWD  26208
#define C_BWD  26720
#define C_U2   27232
#define C_WCS  27360
#define C_RCS  27488    // also ctl_l[256] staging for IF (dead before rcs write)
#define C_MNO  28000
#define C_ERS  28384
#define C_WVS  28448
#define C_SC   28512
#define C_SCAL 28576
#define C_PART2 28608   // 2048 fl: IF partials (4x512), reads partials (4x256)

#define SMEM_FLOATS 36064
#define SMEM_BYTES  (SMEM_FLOATS*4)

// ---- ws layout (floats), state vectors transposed [k][b] ----
#define W_CTL  0       // [256][32]
#define W_RDS  8192    // [256][32]
#define W_H0   16384   // [2][256*32]
#define W_H1   32768   // [2][256*32]
#define W_FLA  49152
#define W_FLB  (W_FLA + 1024)
#define W_FLC  (W_FLB + 1024)
#define W_END  (W_FLC + 1024)

__device__ __forceinline__ float sigf(float x){ return 1.0f/(1.0f+expf(-x)); }
__device__ __forceinline__ float sofp(float x){ return fmaxf(x,0.0f)+log1pf(expf(-fabsf(x))); }

__device__ __forceinline__ float gload(const float* p){
  return __hip_atomic_load(p, __ATOMIC_RELAXED, __HIP_MEMORY_SCOPE_AGENT);
}
__device__ __forceinline__ void gstore(float* p, float v){
  __hip_atomic_store(p, v, __ATOMIC_RELAXED, __HIP_MEMORY_SCOPE_AGENT);
}

__device__ __forceinline__ void waitflag(const unsigned* slots, unsigned target){
  if (threadIdx.x < 64){
    for (;;){
      unsigned m = __hip_atomic_load(&slots[(threadIdx.x & 31)*32],
                                     __ATOMIC_RELAXED, __HIP_MEMORY_SCOPE_AGENT);
      #pragma unroll
      for (int s=32;s>0;s>>=1){
        unsigned o = (unsigned)__shfl_xor((int)m, s, 64);
        m = (o < m) ? o : m;
      }
      if (m >= target) break;
      __builtin_amdgcn_s_sleep(2);
    }
  }
  __syncthreads();
}

__device__ __forceinline__ void setflag(unsigned* slots, int g, unsigned val){
  asm volatile("s_waitcnt vmcnt(0)" ::: "memory");
  __syncthreads();
  if (threadIdx.x == 0)
    __hip_atomic_store(&slots[g*32], val, __ATOMIC_RELAXED, __HIP_MEMORY_SCOPE_AGENT);
}

__device__ __forceinline__ float wredSum(float v){
  #pragma unroll
  for (int m=32;m>0;m>>=1) v += __shfl_xor(v,m,64);
  return v;
}
__device__ __forceinline__ float wredMax(float v){
  #pragma unroll
  for (int m=32;m>0;m>>=1) v = fmaxf(v,__shfl_xor(v,m,64));
  return v;
}

// 6-stage butterfly reduce-scatter over 64 lanes
__device__ __forceinline__ float bfly64(float (&A)[64], int l, int* jb){
  #pragma unroll
  for (int st=0; st<6; ++st){
    const int m = 1<<st, half = 32>>st;
    const bool hi = (l & m) != 0;
    #pragma unroll
    for (int j=0;j<half;j++){
      float a = A[j], b = A[j+half];
      float keep = hi? b : a;
      float send = hi? a : b;
      A[j] = keep + __shfl_xor(send, m, 64);
    }
  }
  *jb = ((l&1)?32:0)|((l&2)?16:0)|((l&4)?8:0)|((l&8)?4:0)|((l&16)?2:0)|((l&32)?1:0);
  return A[0];
}

#define TILE_FMA(WBASE, WROW, XROW)                                      \
  {                                                                      \
    float xv[8], wv[8];                                                  \
    _Pragma("unroll")                                                    \
    for (int q=0;q<8;q++){                                               \
      wv[q] = sm[(WBASE) + (WROW)*37 + c0 + q];                          \
      xv[q] = Xs[(XROW)*37 + b0 + q];                                    \
    }                                                                    \
    _Pragma("unroll")                                                    \
    for (int bi=0;bi<8;bi++)                                             \
      _Pragma("unroll")                                                  \
      for (int ci=0;ci<8;ci++)                                           \
        acc[bi*8+ci] += xv[bi]*wv[ci];                                   \
  }

extern "C" __global__ __launch_bounds__(1024, 1)
void dnc_coop12(const float* __restrict__ inputs,
                const float* __restrict__ Wx0, const float* __restrict__ Wh0, const float* __restrict__ b0g,
                const float* __restrict__ Wx1, const float* __restrict__ Wh1, const float* __restrict__ b1g,
                const float* __restrict__ Wifg, const float* __restrict__ bifg,
                const float* __restrict__ Woutg, const float* __restrict__ boutg,
                float* __restrict__ outg, float* __restrict__ ws)
{
  const int bid  = blockIdx.x;
  const int role = bid >> 5;
  const int g    = bid & 31;
  const int tid  = threadIdx.x;
  const int lane = tid & 63;
  const int wid  = tid >> 6;

  extern __shared__ float sm[];

  float* gctl  = ws + W_CTL;
  float* greads= ws + W_RDS;
  unsigned* fA = (unsigned*)(ws + W_FLA);
  unsigned* fB = (unsigned*)(ws + W_FLB);
  unsigned* fC = (unsigned*)(ws + W_FLC);

  // ---- one-time weight staging + state init ----
  if (role == 0){
    for (int i = tid; i < 576*32; i += 1024){
      int r = i >> 5, cl = i & 31;
      int cglob = 8*g + (cl&7) + ((cl>>3)<<8);
      float v;
      if (r < 256)      v = Wx0[(64+r)*1024 + cglob];
      else if (r < 320) v = Wx0[(r-256)*1024 + cglob];
      else              v = Wh0[(r-320)*1024 + cglob];
      sm[A_WS + r*37 + cl] = v;
    }
    for (int i = tid; i < 512*2; i += 1024){
      int k = i >> 1, c = i & 1;
      sm[A_WO + k*3 + c] = Woutg[k*64 + 2*g + c];
    }
    if (tid < 256) sm[A_C0 + tid] = 0.0f;
  } else if (role == 1){
    for (int i = tid; i < 512*32; i += 1024){
      int r = i >> 5, cl = i & 31;
      int cglob = 8*g + (cl&7) + ((cl>>3)<<8);
      sm[B_W1 + r*37 + cl] = (r < 256) ? Wx1[r*1024 + cglob]
                                       : Wh1[(r-256)*1024 + cglob];
    }
    if (tid < 256) sm[B_C1 + tid] = 0.0f;
  } else {
    for (int i = tid; i < NN*65;  i += 1024) sm[C_MS + i] = 0.0f;
    for (int i = tid; i < NN*129; i += 1024) sm[C_LS + i] = 0.0f;
    if (tid < 128){ sm[C_WW+tid]=0.f; sm[C_PRC+tid]=0.f; sm[C_USG+tid]=0.f; }
    if (tid < 512) sm[C_RWS+tid]=0.f;
  }
  __syncthreads();

  if (role == 0){
    // =================== ROLE A: LSTM0 (+ outproj off-path) — R11 verbatim ===
    float* Xs = sm + A_XS;
    for (int t = 0; t <= TT; ++t){
      float* h0old = ws + W_H0 + (t&1)*8192;
      float* h0new = ws + W_H0 + ((t+1)&1)*8192;
      float acc[64]; float accO[16];

      waitflag(fA, (unsigned)t);
      if (t < TT){
        for (int i = tid; i < 256*32; i += 1024){
          int k = i>>5, bb = i&31; Xs[k*37+bb] = gload(&h0old[i]);
        }
        for (int i = tid; i < 64*32; i += 1024){
          int bb = i>>6, k = i&63;
          Xs[(256+k)*37+bb] = inputs[(t*BB + bb)*INW + k];
        }
        __syncthreads();
        #pragma unroll
        for (int j=0;j<64;j++) acc[j]=0.f;
        {
          const int b0 = (wid>>2)*8, c0 = (wid&3)*8;
          #pragma unroll
          for (int i=0;i<4;i++){
            int k = i*64 + lane;
            TILE_FMA(A_WS, 320+k, k)
          }
          TILE_FMA(A_WS, 256+lane, 256+lane)
        }
        __syncthreads();
      }
      if (t > 0){
        waitflag(fB, (unsigned)t);
        for (int i = tid; i < 256*32; i += 1024){
          int k = i>>5, bb = i&31; Xs[k*37+bb] = gload(&gctl[i]);
        }
        __syncthreads();
        #pragma unroll
        for (int j=0;j<16;j++) accO[j]=0.f;
        if (wid < 4){
          const int b0 = wid*8;
          #pragma unroll
          for (int i=0;i<4;i++){
            int k = i*64 + lane;
            float w0 = sm[A_WO + k*3], w1 = sm[A_WO + k*3 + 1];
            float xv[8];
            #pragma unroll
            for (int q=0;q<8;q++) xv[q] = Xs[k*37 + b0 + q];
            #pragma unroll
            for (int bi=0;bi<8;bi++){
              accO[bi*2]   += xv[bi]*w0;
              accO[bi*2+1] += xv[bi]*w1;
            }
          }
        }
        __syncthreads();
      }
      waitflag(fC, (unsigned)t);
      for (int i = tid; i < 256*32; i += 1024){
        int k = i>>5, bb = i&31; Xs[k*37+bb] = gload(&greads[i]);
      }
      __syncthreads();
      if (t < TT){
        {
          const int b0 = (wid>>2)*8, c0 = (wid&3)*8;
          #pragma unroll
          for (int i=0;i<4;i++){
            int k = i*64 + lane;
            TILE_FMA(A_WS, k, k)
          }
          int jb; float v = bfly64(acc, lane, &jb);
          sm[A_GL + (b0 + (jb>>3))*33 + c0 + (jb&7)] = v;
        }
        __syncthreads();
        if (tid < 256){
          int j = tid>>5, bb = tid&31;
          float gi = sm[A_GL + bb*33 + j]      + b0g[8*g + j];
          float gf = sm[A_GL + bb*33 + 8 + j]  + b0g[256 + 8*g + j];
          float gg = sm[A_GL + bb*33 + 16 + j] + b0g[512 + 8*g + j];
          float go = sm[A_GL + bb*33 + 24 + j] + b0g[768 + 8*g + j];
          float c = sigf(gf)*sm[A_C0 + j*32 + bb] + sigf(gi)*tanhf(gg);
          sm[A_C0 + j*32 + bb] = c;
          gstore(&h0new[256*g + tid], sigf(go)*tanhf(c));
        }
        setflag(fA, g, (unsigned)(t+1));
      }
      if (t > 0){
        if (wid < 4){
          const int b0 = wid*8;
          #pragma unroll
          for (int i=0;i<4;i++){
            int k = i*64 + lane;
            float w0 = sm[A_WO + (256+k)*3], w1 = sm[A_WO + (256+k)*3 + 1];
            float xv[8];
            #pragma unroll
            for (int q=0;q<8;q++) xv[q] = Xs[k*37 + b0 + q];
            #pragma unroll
            for (int bi=0;bi<8;bi++){
              accO[bi*2]   += xv[bi]*w0;
              accO[bi*2+1] += xv[bi]*w1;
            }
          }
          #pragma unroll
          for (int st=0; st<4; ++st){
            const int m = 1<<st, half = 8>>st;
            const bool hi = (lane & m) != 0;
            #pragma unroll
            for (int j=0;j<half;j++){
              float a = accO[j], b = accO[j+half];
              float keep = hi? b : a;
              float send = hi? a : b;
              accO[j] = keep + __shfl_xor(send, m, 64);
            }
          }
          accO[0] += __shfl_xor(accO[0], 16, 64);
          accO[0] += __shfl_xor(accO[0], 32, 64);
          int jb = ((lane&1)?8:0)|((lane&2)?4:0)|((lane&4)?2:0)|((lane&8)?1:0);
          if ((lane & 48) == 0){
            int bi = jb>>1, ci = jb&1;
            sm[A_GO + (wid*8+bi)*2 + ci] = accO[0];
          }
        }
        __syncthreads();
        if (tid < 64){
          int bb = tid>>1, c = tid&1;
          float v = sm[A_GO + tid] + boutg[2*g + c];
          outg[((t-1)*BB + bb)*OUTW + 2*g + c] = fminf(CLIPV, fmaxf(-CLIPV, v));
        }
      }
    }
  } else if (role == 1){
    // =================== ROLE B: LSTM1 — R11 verbatim ===================
    float* Xs = sm + B_XS;
    for (int t = 0; t < TT; ++t){
      float* h0new = ws + W_H0 + ((t+1)&1)*8192;
      float* h1old = ws + W_H1 + (t&1)*8192;
      float* h1new = ws + W_H1 + ((t+1)&1)*8192;
      float acc[64];
      #pragma unroll
      for (int j=0;j<64;j++) acc[j]=0.f;

      waitflag(fB, (unsigned)t);
      for (int i = tid; i < 256*32; i += 1024){
        int k = i>>5, bb = i&31; Xs[k*37+bb] = gload(&h1old[i]);
      }
      __syncthreads();
      {
        const int b0 = (wid>>2)*8, c0 = (wid&3)*8;
        #pragma unroll
        for (int i=0;i<4;i++){
          int k = i*64 + lane;
          TILE_FMA(B_W1, 256+k, k)
        }
      }
      __syncthreads();
      waitflag(fA, (unsigned)(t+1));
      for (int i = tid; i < 256*32; i += 1024){
        int k = i>>5, bb = i&31; Xs[k*37+bb] = gload(&h0new[i]);
      }
      __syncthreads();
      {
        const int b0 = (wid>>2)*8, c0 = (wid&3)*8;
        #pragma unroll
        for (int i=0;i<4;i++){
          int k = i*64 + lane;
          TILE_FMA(B_W1, k, k)
        }
        int jb; float v = bfly64(acc, lane, &jb);
        sm[B_GL + (b0 + (jb>>3))*33 + c0 + (jb&7)] = v;
      }
      __syncthreads();
      if (tid < 256){
        int j = tid>>5, bb = tid&31;
        float gi = sm[B_GL + bb*33 + j]      + b1g[8*g + j];
        float gf = sm[B_GL + bb*33 + 8 + j]  + b1g[256 + 8*g + j];
        float gg = sm[B_GL + bb*33 + 16 + j] + b1g[512 + 8*g + j];
        float go = sm[B_GL + bb*33 + 24 + j] + b1g[768 + 8*g + j];
        float c = sigf(gf)*sm[B_C1 + j*32 + bb] + sigf(gi)*tanhf(gg);
        sm[B_C1 + j*32 + bb] = c;
        float h = sigf(go)*tanhf(c);
        gstore(&h1new[256*g + tid], h);
        gstore(&gctl[256*g + tid], fminf(CLIPV, fmaxf(-CLIPV, h)));
      }
      setflag(fB, g, (unsigned)(t+1));
    }
  } else {
    // =================== ROLE C: compressed module (wide phases) ============
    float* Ms  = sm + C_MS;
    float* Ls  = sm + C_LS;
    float* wws = sm + C_WW;
    float* prc = sm + C_PRC;
    float* usg = sm + C_USG;
    float* rws = sm + C_RWS;
    float* ifcl= sm + C_IFC;
    float* fwds= sm + C_FWD;
    float* bwds= sm + C_BWD;
    float* u2  = sm + C_U2;
    float* wcs = sm + C_WCS;
    float* rcs = sm + C_RCS;
    float* mno = sm + C_MNO;
    float* ers = sm + C_ERS;
    float* wvs = sm + C_WVS;
    float* sc  = sm + C_SC;
    float* scal= sm + C_SCAL;
    float* ctl_l = sm + C_RCS;    // overlay: dead before rcs is written
    float* part2 = sm + C_PART2;  // 2048 fl

    for (int t = 0; t < TT; ++t){
      // idle: ||M(t-1)|| for wc dot
      if (tid < 128){
        float s=0.f;
        #pragma unroll 8
        for (int d=0;d<WD;d++){ float v=Ms[tid*65+d]; s+=v*v; }
        mno[tid]=sqrtf(s);
      }
      waitflag(fB, (unsigned)(t+1));
      if (tid < 256) ctl_l[tid] = gload(&gctl[tid*32 + g]);
      __syncthreads();
      // IF matvec, 4-way k-split (64-deep chains), 2 cols/thread
      {
        const int kq = tid >> 8, c = tid & 255;
        const int c2 = c + 256;
        const bool has2 = (c2 < IFSZ);
        const float* Wp = Wifg + (size_t)(kq*64)*IFSZ;
        const float* xp = ctl_l + kq*64;
        float a0=0.f, a1=0.f;
        #pragma unroll 8
        for (int k=0;k<64;k++){
          float x = xp[k];
          a0 += x * Wp[(size_t)k*IFSZ + c];
          if (has2) a1 += x * Wp[(size_t)k*IFSZ + c2];
        }
        part2[kq*512 + c] = a0;
        if (has2) part2[kq*512 + c2] = a1;
      }
      __syncthreads();
      if (tid < IFSZ)
        ifcl[tid] = part2[tid] + part2[512+tid] + part2[1024+tid] + part2[1536+tid] + bifg[tid];
      __syncthreads();

      // P1: scalars + key norms + ers/wvs (disjoint thread ranges)
      if (tid < RR){
        scal[S_RSTR+tid]=1.0f+sofp(ifcl[OFF_RSTR+tid]);
        scal[S_FG+tid]  =sigf(ifcl[OFF_FG+tid]);
        float m0=ifcl[OFF_MD+tid*3], m1=ifcl[OFF_MD+tid*3+1], m2=ifcl[OFF_MD+tid*3+2];
        float mx=fmaxf(m0,fmaxf(m1,m2));
        float e0=expf(m0-mx), e1=expf(m1-mx), e2=expf(m2-mx);
        float s=e0+e1+e2;
        scal[S_BM+tid]=e0/s; scal[S_FM+tid]=e1/s; scal[S_CM+tid]=e2/s;
      }
      if (tid == 4) scal[S_WSTR]=1.0f+sofp(ifcl[OFF_WSTR]);
      if (tid == 5) scal[S_AG]=sigf(ifcl[OFF_AG]);
      if (tid == 6) scal[S_WG]=sigf(ifcl[OFF_WG]);
      if (tid >= 64 && tid < 128){
        int d=tid-64;
        ers[d]=sigf(ifcl[OFF_ER+d]);
        wvs[d]=ifcl[OFF_WV+d];
      }
      if (wid == 8){
        float v=ifcl[OFF_WK+lane]; float s=wredSum(v*v);
        if (lane==0) scal[S_KNW]=sqrtf(s);
      }
      if (wid >= 10 && wid < 14){
        int r=wid-10; float v=ifcl[OFF_RK+r*WD+lane]; float s=wredSum(v*v);
        if (lane==0) scal[S_KNR+r]=sqrtf(s);
      }
      __syncthreads();

      // P2: wc dot (waves 0-1) || usage+u2 (waves 2-3)
      if (tid < NN){
        float dot=0.f;
        #pragma unroll 8
        for (int d=0;d<WD;d++) dot += ifcl[OFF_WK+d]*Ms[tid*65+d];
        wcs[tid] = dot/(scal[S_KNW]*mno[tid]+EPSV)*scal[S_WSTR];
      } else if (tid < 256){
        int n = tid-128;
        float cw = wws[n];
        float u  = usg[n] + (1.0f-usg[n])*cw;
        float psi=1.0f;
        #pragma unroll
        for (int r=0;r<RR;r++) psi *= 1.0f - scal[S_FG+r]*rws[r*NN+n];
        float us = u*psi;
        usg[n]=us;
        u2[n] = EPSV + (1.0f-EPSV)*us;
      }
      __syncthreads();
      // P2b1: wc wave max
      if (tid < NN){ float mx=wredMax(wcs[tid]); if(lane==0) sc[wid]=mx; }
      __syncthreads();
      // P2b2: exp + wave sum (normalize deferred)
      if (tid < NN){
        float mx=fmaxf(sc[0],sc[1]);
        float e=expf(wcs[tid]-mx);
        wcs[tid]=e;
        float s=wredSum(e); if(lane==0) sc[2+wid]=s;
      }
      __syncthreads();
      // P4: allocation + ww (wc normalize fused) + ww wave-sum
      if (tid < NN){
        float wcsum = sc[2]+sc[3];
        float ui=u2[tid]; float p=1.0f;
        for (int j=0;j<NN;j++){
          float uj=u2[j];
          bool take = (uj<ui) || (uj==ui && j<tid);
          p *= take ? uj : 1.0f;
        }
        float a = (1.0f-ui)*p;
        float wwn = scal[S_WG]*( scal[S_AG]*a + (1.0f-scal[S_AG])*(wcs[tid]/wcsum) );
        wws[tid]=wwn;
        float s=wredSum(wwn); if(lane==0) sc[4+wid]=s;
      }
      __syncthreads();
      // P5: M update + L update (all 1024 threads)
      #pragma unroll
      for (int i=0;i<8;i++){
        int el=tid+i*1024, n=el>>6, d=el&63;
        float w=wws[n];
        Ms[n*65+d] = Ms[n*65+d]*(1.0f - w*ers[d]) + w*wvs[d];
      }
      #pragma unroll
      for (int i=0;i<16;i++){
        int el=tid+i*1024, li=el>>7, lj=el&127;
        float v = (li==lj) ? 0.0f
                : (1.0f - wws[li] - wws[lj])*Ls[li*129+lj] + wws[li]*prc[lj];
        Ls[li*129+lj]=v;
      }
      __syncthreads();
      // P7: rcs dot + fused mnorm (waves 0-7) || fwd/bwd (waves 8-15)
      if (tid < 512){
        int r=tid>>7, n=tid&127;
        float dot=0.f, q=0.f;
        #pragma unroll 8
        for (int d=0;d<WD;d++){
          float m = Ms[n*65+d];
          dot += ifcl[OFF_RK+r*WD+d]*m;
          q   += m*m;
        }
        rcs[tid] = dot/(scal[S_KNR+r]*sqrtf(q)+EPSV)*scal[S_RSTR+r];
      } else {
        int idx=tid-512, r=idx>>7, i=idx&127;
        float f=0.f, bw=0.f;
        const float* rwr = rws + r*NN;
        #pragma unroll 4
        for (int j=0;j<NN;j++){
          float rv=rwr[j];
          f  += Ls[i*129+j]*rv;
          bw += Ls[j*129+i]*rv;
        }
        fwds[idx]=f; bwds[idx]=bw;
      }
      __syncthreads();
      // P8a: rcs wave max
      if (tid < 512){ float mx=wredMax(rcs[tid]); if(lane==0) sc[8+wid]=mx; }
      __syncthreads();
      // P8b: exp + wave sum (normalize deferred)
      if (tid < 512){
        int r=tid>>7;
        float mx=fmaxf(sc[8+r*2],sc[9+r*2]);
        float e=expf(rcs[tid]-mx);
        rcs[tid]=e;
        float s=wredSum(e); if(lane==0) sc[16+wid]=s;
      }
      __syncthreads();
      // P9: rw update (rcs normalize fused, waves 0-7) || prec (wave 8-9)
      if (tid < 512){
        int r=tid>>7;
        float rsum = sc[16+r*2]+sc[17+r*2];
        rws[tid] = scal[S_BM+r]*bwds[tid] + scal[S_CM+r]*(rcs[tid]/rsum) + scal[S_FM+r]*fwds[tid];
      } else if (tid < 640){
        int n = tid-512;
        float wsm = sc[4]+sc[5];
        prc[n] = (1.0f - wsm)*prc[n] + wws[n];
      }
      __syncthreads();
      // P10a: reads partials (all 1024, 4-way k-split, 32-deep chains)
      {
        int kq=tid>>8, j=tid&255, r=j>>6, d=j&63;
        float s=0.f;
        const float* rwr = rws + r*NN + kq*32;
        const float* mp  = Ms + (kq*32)*65 + d;
        #pragma unroll 8
        for (int n=0;n<32;n++) s += rwr[n]*mp[n*65];
        part2[kq*256 + j] = s;
      }
      __syncthreads();
      // P10b: finalize + publish
      if (tid < 256){
        float s = part2[tid]+part2[256+tid]+part2[512+tid]+part2[768+tid];
        gstore(&greads[tid*32 + g], s);
      }
      setflag(fC, g, (unsigned)(t+1));
    }
  }
}

extern "C" void kernel_launch(void* const* d_in, const int* in_sizes, int n_in,
                              void* d_out, int out_size, void* d_ws, size_t ws_size,
                              hipStream_t stream)
{
  const float* inputs=(const float*)d_in[0];
  const float* Wx0   =(const float*)d_in[1];
  const float* Wh0   =(const float*)d_in[2];
  const float* b0    =(const float*)d_in[3];
  const float* Wx1   =(const float*)d_in[4];
  const float* Wh1   =(const float*)d_in[5];
  const float* b1    =(const float*)d_in[6];
  const float* Wif   =(const float*)d_in[7];
  const float* bif   =(const float*)d_in[8];
  const float* Wout  =(const float*)d_in[9];
  const float* bout  =(const float*)d_in[10];
  float* out = (float*)d_out;
  float* ws  = (float*)d_ws;

  hipMemsetAsync(ws, 0, W_END * sizeof(float), stream);

  hipFuncSetAttribute((const void*)dnc_coop12,
                      hipFuncAttributeMaxDynamicSharedMemorySize, SMEM_BYTES);

  void* args[] = { (void*)&inputs, (void*)&Wx0, (void*)&Wh0, (void*)&b0,
                   (void*)&Wx1, (void*)&Wh1, (void*)&b1, (void*)&Wif,
                   (void*)&bif, (void*)&Wout, (void*)&bout, (void*)&out,
                   (void*)&ws };
  hipLaunchCooperativeKernel((void*)dnc_coop12, dim3(NBLK), dim3(1024),
                             args, SMEM_BYTES, stream);
}

// Round 13
// 2894.113 us; speedup vs baseline: 1.8555x; 1.0389x over previous
//
#include <hip/hip_runtime.h>
#include <math.h>

// DNC forward v13 = R12 + coherent-traffic op-count reduction:
// 8B paired atomic loads for all big cross-block stagings, 8B paired stores
// for cell-update publishes, greads layout -> [b][256] (contiguous per C
// block), allocation product split 2-way. Ring structure unchanged.

#define TT   64
#define BB   32
#define INW  64
#define OUTW 64
#define NN   128
#define WD   64
#define RR   4
#define HH   256
#define IFSZ 471
#define CLIPV 20.0f
#define EPSV  1e-6f
#define NBLK 96

// interface vector offsets
#define OFF_RK   0
#define OFF_RSTR 256
#define OFF_WK   260
#define OFF_WSTR 324
#define OFF_ER   325
#define OFF_WV   389
#define OFF_FG   453
#define OFF_AG   457
#define OFF_WG   458
#define OFF_MD   459

// scal slots
#define S_WSTR 0
#define S_AG   1
#define S_WG   2
#define S_KNW  3
#define S_RSTR 8
#define S_FG   12
#define S_KNR  16
#define S_BM   20
#define S_FM   24
#define S_CM   28

// ---- LDS layouts (floats) ----
#define A_XS   0
#define A_GL   11840
#define A_C0   12896
#define A_GO   13152
#define A_WS   13216
#define A_WO   34528
#define B_XS   0
#define B_GL   9472
#define B_C1   10528
#define B_W1   10784
#define C_MS   0
#define C_LS   8320
#define C_WW   24832
#define C_PRC  24960
#define C_USG  25088
#define C_RWS  25216
#define C_IFC  25728
#define C_FWD  26208
#define C_BWD  26720
#define C_U2   27232
#define C_WCS  27360
#define C_RCS  27488    // also ctl_l[256] staging for IF (dead before rcs write)
#define C_MNO  28000
#define C_ERS  28384
#define C_WVS  28448
#define C_SC   28512
#define C_SCAL 28576
#define C_PART2 28608   // 2048 fl: IF partials, alloc partials, reads partials

#define SMEM_FLOATS 36064
#define SMEM_BYTES  (SMEM_FLOATS*4)

// ---- ws layout (floats) ----
#define W_CTL  0       // [256][32]  (k-major, block writes 8 contiguous k-rows)
#define W_RDS  8192    // [32][256]  (batch-major: C block g writes row g)
#define W_H0   16384   // [2][256*32]
#define W_H1   32768   // [2][256*32]
#define W_FLA  49152
#define W_FLB  (W_FLA + 1024)
#define W_FLC  (W_FLB + 1024)
#define W_END  (W_FLC + 1024)

__device__ __forceinline__ float sigf(float x){ return 1.0f/(1.0f+expf(-x)); }
__device__ __forceinline__ float sofp(float x){ return fmaxf(x,0.0f)+log1pf(expf(-fabsf(x))); }

__device__ __forceinline__ float gload(const float* p){
  return __hip_atomic_load(p, __ATOMIC_RELAXED, __HIP_MEMORY_SCOPE_AGENT);
}
__device__ __forceinline__ void gstore(float* p, float v){
  __hip_atomic_store(p, v, __ATOMIC_RELAXED, __HIP_MEMORY_SCOPE_AGENT);
}
__device__ __forceinline__ void gload8(const float* p, float* a, float* b){
  union { unsigned long long u; float f[2]; } w;
  w.u = __hip_atomic_load((const unsigned long long*)p,
                          __ATOMIC_RELAXED, __HIP_MEMORY_SCOPE_AGENT);
  *a = w.f[0]; *b = w.f[1];
}
__device__ __forceinline__ void gstore8(float* p, float a, float b){
  union { unsigned long long u; float f[2]; } w;
  w.f[0]=a; w.f[1]=b;
  __hip_atomic_store((unsigned long long*)p, w.u,
                     __ATOMIC_RELAXED, __HIP_MEMORY_SCOPE_AGENT);
}

__device__ __forceinline__ void waitflag(const unsigned* slots, unsigned target){
  if (threadIdx.x < 64){
    for (;;){
      unsigned m = __hip_atomic_load(&slots[(threadIdx.x & 31)*32],
                                     __ATOMIC_RELAXED, __HIP_MEMORY_SCOPE_AGENT);
      #pragma unroll
      for (int s=32;s>0;s>>=1){
        unsigned o = (unsigned)__shfl_xor((int)m, s, 64);
        m = (o < m) ? o : m;
      }
      if (m >= target) break;
      __builtin_amdgcn_s_sleep(2);
    }
  }
  __syncthreads();
}

__device__ __forceinline__ void setflag(unsigned* slots, int g, unsigned val){
  asm volatile("s_waitcnt vmcnt(0)" ::: "memory");
  __syncthreads();
  if (threadIdx.x == 0)
    __hip_atomic_store(&slots[g*32], val, __ATOMIC_RELAXED, __HIP_MEMORY_SCOPE_AGENT);
}

__device__ __forceinline__ float wredSum(float v){
  #pragma unroll
  for (int m=32;m>0;m>>=1) v += __shfl_xor(v,m,64);
  return v;
}
__device__ __forceinline__ float wredMax(float v){
  #pragma unroll
  for (int m=32;m>0;m>>=1) v = fmaxf(v,__shfl_xor(v,m,64));
  return v;
}

// 6-stage butterfly reduce-scatter over 64 lanes
__device__ __forceinline__ float bfly64(float (&A)[64], int l, int* jb){
  #pragma unroll
  for (int st=0; st<6; ++st){
    const int m = 1<<st, half = 32>>st;
    const bool hi = (l & m) != 0;
    #pragma unroll
    for (int j=0;j<half;j++){
      float a = A[j], b = A[j+half];
      float keep = hi? b : a;
      float send = hi? a : b;
      A[j] = keep + __shfl_xor(send, m, 64);
    }
  }
  *jb = ((l&1)?32:0)|((l&2)?16:0)|((l&4)?8:0)|((l&8)?4:0)|((l&16)?2:0)|((l&32)?1:0);
  return A[0];
}

#define TILE_FMA(WBASE, WROW, XROW)                                      \
  {                                                                      \
    float xv[8], wv[8];                                                  \
    _Pragma("unroll")                                                    \
    for (int q=0;q<8;q++){                                               \
      wv[q] = sm[(WBASE) + (WROW)*37 + c0 + q];                          \
      xv[q] = Xs[(XROW)*37 + b0 + q];                                    \
    }                                                                    \
    _Pragma("unroll")                                                    \
    for (int bi=0;bi<8;bi++)                                             \
      _Pragma("unroll")                                                  \
      for (int ci=0;ci<8;ci++)                                           \
        acc[bi*8+ci] += xv[bi]*wv[ci];                                   \
  }

extern "C" __global__ __launch_bounds__(1024, 1)
void dnc_coop13(const float* __restrict__ inputs,
                const float* __restrict__ Wx0, const float* __restrict__ Wh0, const float* __restrict__ b0g,
                const float* __restrict__ Wx1, const float* __restrict__ Wh1, const float* __restrict__ b1g,
                const float* __restrict__ Wifg, const float* __restrict__ bifg,
                const float* __restrict__ Woutg, const float* __restrict__ boutg,
                float* __restrict__ outg, float* __restrict__ ws)
{
  const int bid  = blockIdx.x;
  const int role = bid >> 5;
  const int g    = bid & 31;
  const int tid  = threadIdx.x;
  const int lane = tid & 63;
  const int wid  = tid >> 6;

  extern __shared__ float sm[];

  float* gctl  = ws + W_CTL;
  float* greads= ws + W_RDS;
  unsigned* fA = (unsigned*)(ws + W_FLA);
  unsigned* fB = (unsigned*)(ws + W_FLB);
  unsigned* fC = (unsigned*)(ws + W_FLC);

  // ---- one-time weight staging + state init ----
  if (role == 0){
    for (int i = tid; i < 576*32; i += 1024){
      int r = i >> 5, cl = i & 31;
      int cglob = 8*g + (cl&7) + ((cl>>3)<<8);
      float v;
      if (r < 256)      v = Wx0[(64+r)*1024 + cglob];
      else if (r < 320) v = Wx0[(r-256)*1024 + cglob];
      else              v = Wh0[(r-320)*1024 + cglob];
      sm[A_WS + r*37 + cl] = v;
    }
    for (int i = tid; i < 512*2; i += 1024){
      int k = i >> 1, c = i & 1;
      sm[A_WO + k*3 + c] = Woutg[k*64 + 2*g + c];
    }
    if (tid < 256) sm[A_C0 + tid] = 0.0f;
  } else if (role == 1){
    for (int i = tid; i < 512*32; i += 1024){
      int r = i >> 5, cl = i & 31;
      int cglob = 8*g + (cl&7) + ((cl>>3)<<8);
      sm[B_W1 + r*37 + cl] = (r < 256) ? Wx1[r*1024 + cglob]
                                       : Wh1[(r-256)*1024 + cglob];
    }
    if (tid < 256) sm[B_C1 + tid] = 0.0f;
  } else {
    for (int i = tid; i < NN*65;  i += 1024) sm[C_MS + i] = 0.0f;
    for (int i = tid; i < NN*129; i += 1024) sm[C_LS + i] = 0.0f;
    if (tid < 128){ sm[C_WW+tid]=0.f; sm[C_PRC+tid]=0.f; sm[C_USG+tid]=0.f; }
    if (tid < 512) sm[C_RWS+tid]=0.f;
  }
  __syncthreads();

  if (role == 0){
    // =================== ROLE A: LSTM0 (+ outproj off-path) ===================
    float* Xs = sm + A_XS;
    for (int t = 0; t <= TT; ++t){
      float* h0old = ws + W_H0 + (t&1)*8192;
      float* h0new = ws + W_H0 + ((t+1)&1)*8192;
      float acc[64]; float accO[16];

      // --- idle-window: h0-chunk + x-chunk ---
      waitflag(fA, (unsigned)t);
      if (t < TT){
        for (int i = tid; i < 256*16; i += 1024){      // 8B pairs along b
          int k = i>>4, b2 = (i&15)*2;
          float x0,x1; gload8(&h0old[k*32+b2], &x0,&x1);
          Xs[k*37+b2]=x0; Xs[k*37+b2+1]=x1;
        }
        for (int i = tid; i < 64*32; i += 1024){
          int bb = i>>6, k = i&63;
          Xs[(256+k)*37+bb] = inputs[(t*BB + bb)*INW + k];
        }
        __syncthreads();
        #pragma unroll
        for (int j=0;j<64;j++) acc[j]=0.f;
        {
          const int b0 = (wid>>2)*8, c0 = (wid&3)*8;
          #pragma unroll
          for (int i=0;i<4;i++){
            int k = i*64 + lane;
            TILE_FMA(A_WS, 320+k, k)
          }
          TILE_FMA(A_WS, 256+lane, 256+lane)
        }
        __syncthreads();
      }
      // --- idle-window: outproj ctl-half ---
      if (t > 0){
        waitflag(fB, (unsigned)t);
        for (int i = tid; i < 256*16; i += 1024){
          int k = i>>4, b2 = (i&15)*2;
          float x0,x1; gload8(&gctl[k*32+b2], &x0,&x1);
          Xs[k*37+b2]=x0; Xs[k*37+b2+1]=x1;
        }
        __syncthreads();
        #pragma unroll
        for (int j=0;j<16;j++) accO[j]=0.f;
        if (wid < 4){
          const int b0 = wid*8;
          #pragma unroll
          for (int i=0;i<4;i++){
            int k = i*64 + lane;
            float w0 = sm[A_WO + k*3], w1 = sm[A_WO + k*3 + 1];
            float xv[8];
            #pragma unroll
            for (int q=0;q<8;q++) xv[q] = Xs[k*37 + b0 + q];
            #pragma unroll
            for (int bi=0;bi<8;bi++){
              accO[bi*2]   += xv[bi]*w0;
              accO[bi*2+1] += xv[bi]*w1;
            }
          }
        }
        __syncthreads();
      }
      // --- critical path: reads(t-1), layout [b][256] ---
      waitflag(fC, (unsigned)t);
      for (int i = tid; i < 32*128; i += 1024){
        int b = i>>7, k2 = (i&127)*2;
        float x0,x1; gload8(&greads[b*256+k2], &x0,&x1);
        Xs[k2*37+b]=x0; Xs[(k2+1)*37+b]=x1;
      }
      __syncthreads();
      if (t < TT){
        {
          const int b0 = (wid>>2)*8, c0 = (wid&3)*8;
          #pragma unroll
          for (int i=0;i<4;i++){
            int k = i*64 + lane;
            TILE_FMA(A_WS, k, k)
          }
          int jb; float v = bfly64(acc, lane, &jb);
          sm[A_GL + (b0 + (jb>>3))*33 + c0 + (jb&7)] = v;
        }
        __syncthreads();
        if (tid < 128){
          int t2 = tid*2, j = t2>>5, bb = t2&31;
          float hv[2];
          #pragma unroll
          for (int q=0;q<2;q++){
            int b_ = bb+q;
            float gi = sm[A_GL + b_*33 + j]      + b0g[8*g + j];
            float gf = sm[A_GL + b_*33 + 8 + j]  + b0g[256 + 8*g + j];
            float gg = sm[A_GL + b_*33 + 16 + j] + b0g[512 + 8*g + j];
            float go = sm[A_GL + b_*33 + 24 + j] + b0g[768 + 8*g + j];
            float c = sigf(gf)*sm[A_C0 + j*32 + b_] + sigf(gi)*tanhf(gg);
            sm[A_C0 + j*32 + b_] = c;
            hv[q] = sigf(go)*tanhf(c);
          }
          gstore8(&h0new[256*g + t2], hv[0], hv[1]);
        }
        setflag(fA, g, (unsigned)(t+1));
      }
      // --- off-critical: finish outproj(t-1) ---
      if (t > 0){
        if (wid < 4){
          const int b0 = wid*8;
          #pragma unroll
          for (int i=0;i<4;i++){
            int k = i*64 + lane;
            float w0 = sm[A_WO + (256+k)*3], w1 = sm[A_WO + (256+k)*3 + 1];
            float xv[8];
            #pragma unroll
            for (int q=0;q<8;q++) xv[q] = Xs[k*37 + b0 + q];
            #pragma unroll
            for (int bi=0;bi<8;bi++){
              accO[bi*2]   += xv[bi]*w0;
              accO[bi*2+1] += xv[bi]*w1;
            }
          }
          #pragma unroll
          for (int st=0; st<4; ++st){
            const int m = 1<<st, half = 8>>st;
            const bool hi = (lane & m) != 0;
            #pragma unroll
            for (int j=0;j<half;j++){
              float a = accO[j], b = accO[j+half];
              float keep = hi? b : a;
              float send = hi? a : b;
              accO[j] = keep + __shfl_xor(send, m, 64);
            }
          }
          accO[0] += __shfl_xor(accO[0], 16, 64);
          accO[0] += __shfl_xor(accO[0], 32, 64);
          int jb = ((lane&1)?8:0)|((lane&2)?4:0)|((lane&4)?2:0)|((lane&8)?1:0);
          if ((lane & 48) == 0){
            int bi = jb>>1, ci = jb&1;
            sm[A_GO + (wid*8+bi)*2 + ci] = accO[0];
          }
        }
        __syncthreads();
        if (tid < 64){
          int bb = tid>>1, c = tid&1;
          float v = sm[A_GO + tid] + boutg[2*g + c];
          outg[((t-1)*BB + bb)*OUTW + 2*g + c] = fminf(CLIPV, fmaxf(-CLIPV, v));
        }
      }
    }
  } else if (role == 1){
    // =================== ROLE B: LSTM1 ===================
    float* Xs = sm + B_XS;
    for (int t = 0; t < TT; ++t){
      float* h0new = ws + W_H0 + ((t+1)&1)*8192;
      float* h1old = ws + W_H1 + (t&1)*8192;
      float* h1new = ws + W_H1 + ((t+1)&1)*8192;
      float acc[64];
      #pragma unroll
      for (int j=0;j<64;j++) acc[j]=0.f;

      waitflag(fB, (unsigned)t);
      for (int i = tid; i < 256*16; i += 1024){
        int k = i>>4, b2 = (i&15)*2;
        float x0,x1; gload8(&h1old[k*32+b2], &x0,&x1);
        Xs[k*37+b2]=x0; Xs[k*37+b2+1]=x1;
      }
      __syncthreads();
      {
        const int b0 = (wid>>2)*8, c0 = (wid&3)*8;
        #pragma unroll
        for (int i=0;i<4;i++){
          int k = i*64 + lane;
          TILE_FMA(B_W1, 256+k, k)
        }
      }
      __syncthreads();
      waitflag(fA, (unsigned)(t+1));
      for (int i = tid; i < 256*16; i += 1024){
        int k = i>>4, b2 = (i&15)*2;
        float x0,x1; gload8(&h0new[k*32+b2], &x0,&x1);
        Xs[k*37+b2]=x0; Xs[k*37+b2+1]=x1;
      }
      __syncthreads();
      {
        const int b0 = (wid>>2)*8, c0 = (wid&3)*8;
        #pragma unroll
        for (int i=0;i<4;i++){
          int k = i*64 + lane;
          TILE_FMA(B_W1, k, k)
        }
        int jb; float v = bfly64(acc, lane, &jb);
        sm[B_GL + (b0 + (jb>>3))*33 + c0 + (jb&7)] = v;
      }
      __syncthreads();
      if (tid < 128){
        int t2 = tid*2, j = t2>>5, bb = t2&31;
        float hv[2], cl2[2];
        #pragma unroll
        for (int q=0;q<2;q++){
          int b_ = bb+q;
          float gi = sm[B_GL + b_*33 + j]      + b1g[8*g + j];
          float gf = sm[B_GL + b_*33 + 8 + j]  + b1g[256 + 8*g + j];
          float gg = sm[B_GL + b_*33 + 16 + j] + b1g[512 + 8*g + j];
          float go = sm[B_GL + b_*33 + 24 + j] + b1g[768 + 8*g + j];
          float c = sigf(gf)*sm[B_C1 + j*32 + b_] + sigf(gi)*tanhf(gg);
          sm[B_C1 + j*32 + b_] = c;
          float h = sigf(go)*tanhf(c);
          hv[q] = h;
          cl2[q] = fminf(CLIPV, fmaxf(-CLIPV, h));
        }
        gstore8(&h1new[256*g + t2], hv[0], hv[1]);
        gstore8(&gctl[256*g + t2], cl2[0], cl2[1]);
      }
      setflag(fB, g, (unsigned)(t+1));
    }
  } else {
    // =================== ROLE C: compressed module (wide phases) ============
    float* Ms  = sm + C_MS;
    float* Ls  = sm + C_LS;
    float* wws = sm + C_WW;
    float* prc = sm + C_PRC;
    float* usg = sm + C_USG;
    float* rws = sm + C_RWS;
    float* ifcl= sm + C_IFC;
    float* fwds= sm + C_FWD;
    float* bwds= sm + C_BWD;
    float* u2  = sm + C_U2;
    float* wcs = sm + C_WCS;
    float* rcs = sm + C_RCS;
    float* mno = sm + C_MNO;
    float* ers = sm + C_ERS;
    float* wvs = sm + C_WVS;
    float* sc  = sm + C_SC;
    float* scal= sm + C_SCAL;
    float* ctl_l = sm + C_RCS;    // overlay: dead before rcs is written
    float* part2 = sm + C_PART2;  // 2048 fl

    for (int t = 0; t < TT; ++t){
      // idle: ||M(t-1)|| for wc dot
      if (tid < 128){
        float s=0.f;
        #pragma unroll 8
        for (int d=0;d<WD;d++){ float v=Ms[tid*65+d]; s+=v*v; }
        mno[tid]=sqrtf(s);
      }
      waitflag(fB, (unsigned)(t+1));
      if (tid < 256) ctl_l[tid] = gload(&gctl[tid*32 + g]);
      __syncthreads();
      // IF matvec, 4-way k-split (64-deep chains), 2 cols/thread
      {
        const int kq = tid >> 8, c = tid & 255;
        const int c2 = c + 256;
        const bool has2 = (c2 < IFSZ);
        const float* Wp = Wifg + (size_t)(kq*64)*IFSZ;
        const float* xp = ctl_l + kq*64;
        float a0=0.f, a1=0.f;
        #pragma unroll 8
        for (int k=0;k<64;k++){
          float x = xp[k];
          a0 += x * Wp[(size_t)k*IFSZ + c];
          if (has2) a1 += x * Wp[(size_t)k*IFSZ + c2];
        }
        part2[kq*512 + c] = a0;
        if (has2) part2[kq*512 + c2] = a1;
      }
      __syncthreads();
      if (tid < IFSZ)
        ifcl[tid] = part2[tid] + part2[512+tid] + part2[1024+tid] + part2[1536+tid] + bifg[tid];
      __syncthreads();

      // P1: scalars + key norms + ers/wvs
      if (tid < RR){
        scal[S_RSTR+tid]=1.0f+sofp(ifcl[OFF_RSTR+tid]);
        scal[S_FG+tid]  =sigf(ifcl[OFF_FG+tid]);
        float m0=ifcl[OFF_MD+tid*3], m1=ifcl[OFF_MD+tid*3+1], m2=ifcl[OFF_MD+tid*3+2];
        float mx=fmaxf(m0,fmaxf(m1,m2));
        float e0=expf(m0-mx), e1=expf(m1-mx), e2=expf(m2-mx);
        float s=e0+e1+e2;
        scal[S_BM+tid]=e0/s; scal[S_FM+tid]=e1/s; scal[S_CM+tid]=e2/s;
      }
      if (tid == 4) scal[S_WSTR]=1.0f+sofp(ifcl[OFF_WSTR]);
      if (tid == 5) scal[S_AG]=sigf(ifcl[OFF_AG]);
      if (tid == 6) scal[S_WG]=sigf(ifcl[OFF_WG]);
      if (tid >= 64 && tid < 128){
        int d=tid-64;
        ers[d]=sigf(ifcl[OFF_ER+d]);
        wvs[d]=ifcl[OFF_WV+d];
      }
      if (wid == 8){
        float v=ifcl[OFF_WK+lane]; float s=wredSum(v*v);
        if (lane==0) scal[S_KNW]=sqrtf(s);
      }
      if (wid >= 10 && wid < 14){
        int r=wid-10; float v=ifcl[OFF_RK+r*WD+lane]; float s=wredSum(v*v);
        if (lane==0) scal[S_KNR+r]=sqrtf(s);
      }
      __syncthreads();

      // P2: wc dot (waves 0-1) || usage+u2 (waves 2-3)
      if (tid < NN){
        float dot=0.f;
        #pragma unroll 8
        for (int d=0;d<WD;d++) dot += ifcl[OFF_WK+d]*Ms[tid*65+d];
        wcs[tid] = dot/(scal[S_KNW]*mno[tid]+EPSV)*scal[S_WSTR];
      } else if (tid < 256){
        int n = tid-128;
        float cw = wws[n];
        float u  = usg[n] + (1.0f-usg[n])*cw;
        float psi=1.0f;
        #pragma unroll
        for (int r=0;r<RR;r++) psi *= 1.0f - scal[S_FG+r]*rws[r*NN+n];
        float us = u*psi;
        usg[n]=us;
        u2[n] = EPSV + (1.0f-EPSV)*us;
      }
      __syncthreads();
      if (tid < NN){ float mx=wredMax(wcs[tid]); if(lane==0) sc[wid]=mx; }
      __syncthreads();
      if (tid < NN){
        float mx=fmaxf(sc[0],sc[1]);
        float e=expf(wcs[tid]-mx);
        wcs[tid]=e;
        float s=wredSum(e); if(lane==0) sc[2+wid]=s;
      }
      __syncthreads();
      // P4a: allocation partial products (256 threads x 64 iters)
      if (tid < 256){
        int n = tid & 127, h = tid >> 7;
        float ui = u2[n]; float p = 1.0f;
        int j0 = h*64;
        for (int j=j0; j<j0+64; j++){
          float uj = u2[j];
          bool take = (uj<ui) || (uj==ui && j<n);
          p *= take ? uj : 1.0f;
        }
        part2[h*128 + n] = p;
      }
      __syncthreads();
      // P4b: combine + ww + wave sum
      if (tid < NN){
        float wcsum = sc[2]+sc[3];
        float ui=u2[tid];
        float p = part2[tid]*part2[128+tid];
        float a = (1.0f-ui)*p;
        float wwn = scal[S_WG]*( scal[S_AG]*a + (1.0f-scal[S_AG])*(wcs[tid]/wcsum) );
        wws[tid]=wwn;
        float s=wredSum(wwn); if(lane==0) sc[4+wid]=s;
      }
      __syncthreads();
      // P5: M update + L update
      #pragma unroll
      for (int i=0;i<8;i++){
        int el=tid+i*1024, n=el>>6, d=el&63;
        float w=wws[n];
        Ms[n*65+d] = Ms[n*65+d]*(1.0f - w*ers[d]) + w*wvs[d];
      }
      #pragma unroll
      for (int i=0;i<16;i++){
        int el=tid+i*1024, li=el>>7, lj=el&127;
        float v = (li==lj) ? 0.0f
                : (1.0f - wws[li] - wws[lj])*Ls[li*129+lj] + wws[li]*prc[lj];
        Ls[li*129+lj]=v;
      }
      __syncthreads();
      // P7: rcs dot + fused mnorm (waves 0-7) || fwd/bwd (waves 8-15)
      if (tid < 512){
        int r=tid>>7, n=tid&127;
        float dot=0.f, q=0.f;
        #pragma unroll 8
        for (int d=0;d<WD;d++){
          float m = Ms[n*65+d];
          dot += ifcl[OFF_RK+r*WD+d]*m;
          q   += m*m;
        }
        rcs[tid] = dot/(scal[S_KNR+r]*sqrtf(q)+EPSV)*scal[S_RSTR+r];
      } else {
        int idx=tid-512, r=idx>>7, i=idx&127;
        float f=0.f, bw=0.f;
        const float* rwr = rws + r*NN;
        #pragma unroll 4
        for (int j=0;j<NN;j++){
          float rv=rwr[j];
          f  += Ls[i*129+j]*rv;
          bw += Ls[j*129+i]*rv;
        }
        fwds[idx]=f; bwds[idx]=bw;
      }
      __syncthreads();
      if (tid < 512){ float mx=wredMax(rcs[tid]); if(lane==0) sc[8+wid]=mx; }
      __syncthreads();
      if (tid < 512){
        int r=tid>>7;
        float mx=fmaxf(sc[8+r*2],sc[9+r*2]);
        float e=expf(rcs[tid]-mx);
        rcs[tid]=e;
        float s=wredSum(e); if(lane==0) sc[16+wid]=s;
      }
      __syncthreads();
      // P9: rw update (waves 0-7) || prec (waves 8-9)
      if (tid < 512){
        int r=tid>>7;
        float rsum = sc[16+r*2]+sc[17+r*2];
        rws[tid] = scal[S_BM+r]*bwds[tid] + scal[S_CM+r]*(rcs[tid]/rsum) + scal[S_FM+r]*fwds[tid];
      } else if (tid < 640){
        int n = tid-512;
        float wsm = sc[4]+sc[5];
        prc[n] = (1.0f - wsm)*prc[n] + wws[n];
      }
      __syncthreads();
      // P10a: reads partials (all 1024, 4-way k-split)
      {
        int kq=tid>>8, j=tid&255, r=j>>6, d=j&63;
        float s=0.f;
        const float* rwr = rws + r*NN + kq*32;
        const float* mp  = Ms + (kq*32)*65 + d;
        #pragma unroll 8
        for (int n=0;n<32;n++) s += rwr[n]*mp[n*65];
        part2[kq*256 + j] = s;
      }
      __syncthreads();
      // P10b: finalize + publish as 8B pairs into [b][256] layout
      if (tid < 128){
        int k2 = tid*2;
        float s0 = part2[k2]  +part2[256+k2]  +part2[512+k2]  +part2[768+k2];
        float s1 = part2[k2+1]+part2[256+k2+1]+part2[512+k2+1]+part2[768+k2+1];
        gstore8(&greads[g*256 + k2], s0, s1);
      }
      setflag(fC, g, (unsigned)(t+1));
    }
  }
}

extern "C" void kernel_launch(void* const* d_in, const int* in_sizes, int n_in,
                              void* d_out, int out_size, void* d_ws, size_t ws_size,
                              hipStream_t stream)
{
  const float* inputs=(const float*)d_in[0];
  const float* Wx0   =(const float*)d_in[1];
  const float* Wh0   =(const float*)d_in[2];
  const float* b0    =(const float*)d_in[3];
  const float* Wx1   =(const float*)d_in[4];
  const float* Wh1   =(const float*)d_in[5];
  const float* b1    =(const float*)d_in[6];
  const float* Wif   =(const float*)d_in[7];
  const float* bif   =(const float*)d_in[8];
  const float* Wout  =(const float*)d_in[9];
  const float* bout  =(const float*)d_in[10];
  float* out = (float*)d_out;
  float* ws  = (float*)d_ws;

  hipMemsetAsync(ws, 0, W_END * sizeof(float), stream);

  hipFuncSetAttribute((const void*)dnc_coop13,
                      hipFuncAttributeMaxDynamicSharedMemorySize, SMEM_BYTES);

  void* args[] = { (void*)&inputs, (void*)&Wx0, (void*)&Wh0, (void*)&b0,
                   (void*)&Wx1, (void*)&Wh1, (void*)&b1, (void*)&Wif,
                   (void*)&bif, (void*)&Wout, (void*)&bout, (void*)&out,
                   (void*)&ws };
  hipLaunchCooperativeKernel((void*)dnc_coop13, dim3(NBLK), dim3(1024),
                             args, SMEM_BYTES, stream);
}